// Round 13
// baseline (282.992 us; speedup 1.0000x reference)
//
#include <hip/hip_runtime.h>
#include <hip/hip_bf16.h>
#include <stdint.h>

typedef unsigned short ushort_t;
typedef __attribute__((ext_vector_type(8))) short short8;
typedef __attribute__((ext_vector_type(4))) float floatx4;

#define DEV __device__ __forceinline__

DEV ushort_t f2b(float f) {
  uint32_t x = __float_as_uint(f);
  uint32_t r = (x + 0x7FFFu + ((x >> 16) & 1u)) >> 16;
  return (ushort_t)r;
}
DEV float b2f(ushort_t u) { return __uint_as_float(((uint32_t)u) << 16); }

DEV void async16(const ushort_t* g, ushort_t* l) {
  __builtin_amdgcn_global_load_lds(
      (const __attribute__((address_space(1))) void*)g,
      (__attribute__((address_space(3))) void*)l, 16, 0, 0);
}

// ---------------- fused fp32 -> bf16 conversion (one launch) ----------------
struct Cvt7 {
  const float* src[7];
  ushort_t* dst[7];
  float scale[7];
  unsigned start[8];  // prefix, in float4 units
};
__global__ void cvt_all(Cvt7 a) {
  unsigned idx = blockIdx.x * blockDim.x + threadIdx.x;
  if (idx >= a.start[7]) return;
  int seg = 0;
#pragma unroll
  for (int j = 1; j < 7; j++) seg += (idx >= a.start[j]) ? 1 : 0;
  unsigned off = idx - a.start[seg];
  float sc = a.scale[seg];
  float4 v = ((const float4*)a.src[seg])[off];
  ((ushort4*)a.dst[seg])[off] =
      make_ushort4(f2b(v.x * sc), f2b(v.y * sc), f2b(v.z * sc), f2b(v.w * sc));
}

// ---------------- legacy 128-wide bf16 GEMM ---------------------------------
// C[M,N] = A[M,K=ldk]*B[N,ldk]^T. Tile (32*MT)x128, 256 thr, BK=64, 2-barrier.
// Session-final (R23 = R11, best measured 279.3us). Closed trails:
//  - 6 K-loop schedules all ~26-27% MfmaUtil at K=1024 (2-phase ceiling).
//  - MLP-out: split2+reduce2 < atomic < non-split < MT=4/SWZ0 (A-locality).
//  - Traffic shuffling between stream-ordered kernels: 3x null.
// MODE 1: outB = bf16(acc); outF = acc + bias   (mid; WOb pre-scaled x2)
// MODE 3: outF[z*M*N+idx] = acc                 (MLP-out split-K partials)
template <int MODE, int MT, int SWZ>
__launch_bounds__(256)
__global__ void gemm_bt(const ushort_t* __restrict__ A, const ushort_t* __restrict__ Bm,
                        int M, int N, int Kd, int ldk,
                        ushort_t* __restrict__ outB, float* __restrict__ outF,
                        const float* __restrict__ bias) {
  constexpr int TM = 32 * MT;
  __shared__ alignas(16) ushort_t As[TM * 64];
  __shared__ alignas(16) ushort_t Bs[128 * 64];
  const int tid = threadIdx.x;
  const int wave = tid >> 6, lane = tid & 63;
  const int wm = wave >> 1, wn = wave & 1;

  int bx, by;
  if constexpr (SWZ == 1) {
    const int f = blockIdx.x + gridDim.x * blockIdx.y;
    by = (f & 7) + 8 * (f / (8 * gridDim.x));
    bx = (f >> 3) % gridDim.x;
  } else if constexpr (SWZ == 2) {
    const int x = blockIdx.x, y = blockIdx.y;  // gx=8: XCD = x
    bx = 2 * (x & 3) + (y & 1);
    by = (y >> 1) + 32 * (x >> 2);
  } else {
    bx = blockIdx.x; by = blockIdx.y;
  }
  const int m0 = by * TM, n0 = bx * 128;
  const int kz = blockIdx.z * Kd;

  floatx4 acc[MT][4];
#pragma unroll
  for (int i = 0; i < MT; i++)
#pragma unroll
    for (int j = 0; j < 4; j++) acc[i][j] = (floatx4){0.f, 0.f, 0.f, 0.f};

  const int r8 = lane >> 3;
  const int scol = (((lane & 7) ^ (r8 & 7)) * 8);
  const ushort_t* gA = A + (size_t)(m0 + wave * (TM / 4) + r8) * ldk + kz + scol;
  const ushort_t* gB = Bm + (size_t)(n0 + wave * 32 + r8) * ldk + kz + scol;
  ushort_t* lA = As + wave * (TM / 4) * 64;
  ushort_t* lB = Bs + wave * 2048;

  const int fr = lane & 15, fq = lane >> 4;
  const int sw = fr & 7;
  const ushort_t* rdA = As + (wm * 16 * MT + fr) * 64;
  const ushort_t* rdB = Bs + (wn * 64 + fr) * 64;

  for (int k0 = 0; k0 < Kd; k0 += 64) {
#pragma unroll
    for (int j = 0; j < MT; j++) async16(gA + (size_t)j * 8 * ldk, lA + j * 512);
#pragma unroll
    for (int j = 0; j < 4; j++) async16(gB + (size_t)j * 8 * ldk, lB + j * 512);
    gA += 64; gB += 64;
    __syncthreads();
#pragma unroll
    for (int h = 0; h < 2; h++) {
      const int co = ((h * 4 + fq) ^ sw) * 8;
      short8 af[MT], bfv[4];
#pragma unroll
      for (int mt = 0; mt < MT; mt++) af[mt] = *(const short8*)(rdA + mt * 16 * 64 + co);
#pragma unroll
      for (int nt = 0; nt < 4; nt++) bfv[nt] = *(const short8*)(rdB + nt * 16 * 64 + co);
#pragma unroll
      for (int mt = 0; mt < MT; mt++)
#pragma unroll
        for (int nt = 0; nt < 4; nt++)
          acc[mt][nt] = __builtin_amdgcn_mfma_f32_16x16x32_bf16(af[mt], bfv[nt], acc[mt][nt], 0, 0, 0);
    }
    __syncthreads();
  }

  const int crow = m0 + wm * 16 * MT + (lane >> 4) * 4;
  const int ccol = n0 + wn * 64 + (lane & 15);
  const size_t zoff = (size_t)blockIdx.z * M * N;
#pragma unroll
  for (int mt = 0; mt < MT; mt++)
#pragma unroll
    for (int nt = 0; nt < 4; nt++) {
      floatx4 a = acc[mt][nt];
#pragma unroll
      for (int r = 0; r < 4; r++) {
        const int gm = crow + mt * 16 + r;
        const int gn = ccol + nt * 16;
        const size_t idx = (size_t)gm * N + gn;
        float v = a[r];
        if constexpr (MODE == 0) {
          outB[idx] = f2b(v);
        } else if constexpr (MODE == 1) {
          outB[idx] = f2b(v);          // WOb pre-scaled by 2 in cvt
          outF[idx] = v + bias[gn];
        } else if constexpr (MODE == 2) {
          float t = v + bias[gn];
          outB[idx] = f2b(t > 0.f ? t : 0.f);
        } else {
          outF[zoff + idx] = v;
        }
      }
    }
}

// ---------------- 256x256 pipelined bf16 GEMM (R11 schedule) ----------------
// Best measured for QKV (48.2us) and MLP-in (46-48us). 128KB LDS.
// MODE 0: bf16(acc)   MODE 2: bf16(relu(acc+bias))
template <int MODE>
__launch_bounds__(512, 2)
__global__ void gemm256(const ushort_t* __restrict__ A, const ushort_t* __restrict__ Bm,
                        int M, int N, int Kd, int ldk,
                        ushort_t* __restrict__ outB, float* __restrict__ outF,
                        const float* __restrict__ bias) {
  __shared__ alignas(16) ushort_t As[4][256 * 32];
  __shared__ alignas(16) ushort_t Bs[4][256 * 32];
  const int tid = threadIdx.x;
  const int lane = tid & 63;
  const int wave = tid >> 6;
  const int wm = wave >> 2, wn = wave & 3;

  // bijective XCD-chunk swizzle on the flat (x,y) id (m204 form).
  const int gy = gridDim.y;
  int f = blockIdx.x + gridDim.x * blockIdx.y;
  {
    const int nwg = gridDim.x * gy;
    const int q = nwg >> 3, rr = nwg & 7;
    const int xcd = f & 7, ix = f >> 3;
    f = (xcd < rr ? xcd * (q + 1) : rr * (q + 1) + (xcd - rr) * q) + ix;
  }
  const int bx = f / gy, by = f - gy * bx;
  const int m0 = by * 256, n0 = bx * 256;
  const size_t kz = (size_t)blockIdx.z * Kd;

  floatx4 acc[8][4];
#pragma unroll
  for (int i = 0; i < 8; i++)
#pragma unroll
    for (int j = 0; j < 4; j++) acc[i][j] = (floatx4){0.f, 0.f, 0.f, 0.f};

  const int rloc = tid >> 2, cch = tid & 3;
  const int gcol = ((cch ^ ((rloc >> 1) & 3)) * 8);
  const ushort_t* gA = A + (size_t)(m0 + rloc) * ldk + kz + gcol;
  const ushort_t* gB = Bm + (size_t)(n0 + rloc) * ldk + kz + gcol;
  const int lofs = rloc * 32 + cch * 8;

#define STGA32(bufi, kofs)                                              \
  {                                                                     \
    async16(gA + (kofs), &As[bufi][lofs]);                              \
    async16(gA + (size_t)128 * ldk + (kofs), &As[bufi][4096 + lofs]);   \
  }
#define STGB32(bufi, kofs)                                              \
  {                                                                     \
    async16(gB + (kofs), &Bs[bufi][lofs]);                              \
    async16(gB + (size_t)128 * ldk + (kofs), &Bs[bufi][4096 + lofs]);   \
  }

  const int NT = Kd >> 5;  // K-tiles of 32
  STGA32(0, 0) STGB32(0, 0)
  if (NT > 1) { STGA32(1, 32) STGB32(1, 32) }
  if (NT > 2) { STGA32(2, 64) STGB32(2, 64) }
  if (NT > 2) asm volatile("s_waitcnt vmcnt(8)" ::: "memory");
  else if (NT > 1) asm volatile("s_waitcnt vmcnt(4)" ::: "memory");
  else asm volatile("s_waitcnt vmcnt(0)" ::: "memory");
  __builtin_amdgcn_s_barrier();

  const int fr = lane & 15, fq = lane >> 4;
  const int co = ((fq ^ ((fr >> 1) & 3)) * 8);
  const int aoff = (wm * 128 + fr) * 32 + co;
  const int boff = (wn * 64 + fr) * 32 + co;

  for (int kt = 0; kt < NT; ++kt) {
    const int cb = kt & 3;            // compute slot
    const int pb = (kt + 3) & 3;      // prefetch slot (== (kt-1)&3, freed)
    const int kof = (kt + 3) * 32;
    const bool sp = (kt + 3) < NT;
    const ushort_t* Ab = As[cb];
    const ushort_t* Bb = Bs[cb];
    short8 av[4], bv[4];

    // ---- phase 0: QM=0 (rows wm*128..+64), all 4 n-frags ----
#pragma unroll
    for (int i = 0; i < 4; i++) av[i] = *(const short8*)(Ab + aoff + i * 512);
#pragma unroll
    for (int j = 0; j < 4; j++) bv[j] = *(const short8*)(Bb + boff + j * 512);
    if (sp) STGA32(pb, kof)
    __builtin_amdgcn_s_barrier();
    asm volatile("s_waitcnt lgkmcnt(0)" ::: "memory");
    __builtin_amdgcn_s_setprio(1);
#pragma unroll
    for (int i = 0; i < 4; i++)
#pragma unroll
      for (int j = 0; j < 4; j++)
        acc[i][j] = __builtin_amdgcn_mfma_f32_16x16x32_bf16(av[i], bv[j], acc[i][j], 0, 0, 0);
    __builtin_amdgcn_s_setprio(0);
    __builtin_amdgcn_s_barrier();

    // ---- phase 1: QM=1 (rows wm*128+64..+64), reuse bv ----
#pragma unroll
    for (int i = 0; i < 4; i++) av[i] = *(const short8*)(Ab + aoff + 2048 + i * 512);
    if (sp) STGB32(pb, kof)
    __builtin_amdgcn_s_barrier();
    asm volatile("s_waitcnt lgkmcnt(0)" ::: "memory");
    __builtin_amdgcn_s_setprio(1);
#pragma unroll
    for (int i = 0; i < 4; i++)
#pragma unroll
      for (int j = 0; j < 4; j++)
        acc[4 + i][j] = __builtin_amdgcn_mfma_f32_16x16x32_bf16(av[i], bv[j], acc[4 + i][j], 0, 0, 0);
    __builtin_amdgcn_s_setprio(0);
    if (kt + 3 < NT) asm volatile("s_waitcnt vmcnt(8)" ::: "memory");
    else if (kt + 2 < NT) asm volatile("s_waitcnt vmcnt(4)" ::: "memory");
    else asm volatile("s_waitcnt vmcnt(0)" ::: "memory");
    __builtin_amdgcn_s_barrier();
  }
#undef STGA32
#undef STGB32

  const int crow = m0 + wm * 128 + (lane >> 4) * 4;
  const int ccol = n0 + wn * 64 + (lane & 15);
#pragma unroll
  for (int mt = 0; mt < 8; mt++)
#pragma unroll
    for (int nt = 0; nt < 4; nt++) {
      floatx4 a = acc[mt][nt];
#pragma unroll
      for (int r = 0; r < 4; r++) {
        const int gm = crow + mt * 16 + r;
        const int gn = ccol + nt * 16;
        const size_t idx = (size_t)gm * N + gn;
        if constexpr (MODE == 0) {
          outB[idx] = f2b(a[r]);
        } else if constexpr (MODE == 2) {
          float t = a[r] + bias[gn];
          outB[idx] = f2b(t > 0.f ? t : 0.f);
        } else {
          outF[idx] = a[r];
        }
      }
    }
}

// ---------------- split-K=2 reduction: out += P0 + P1 -----------------------
__launch_bounds__(256)
__global__ void reduce2(const float4* __restrict__ P, float4* __restrict__ out, int n4) {
  int i = blockIdx.x * blockDim.x + threadIdx.x;
  int st = gridDim.x * blockDim.x;
  for (; i < n4; i += st) {
    float4 a = out[i];
    float4 p0 = P[i], p1 = P[i + 1048576];
    a.x += p0.x + p1.x;
    a.y += p0.y + p1.y;
    a.z += p0.z + p1.z;
    a.w += p0.w + p1.w;
    out[i] = a;
  }
}

// ---------------- attention (degenerate mask -> diag + suffix sum) ----------
// z[q] = (e_q*v[q] + sum_{p>q} v[p]) / (e_q + (S-1-q)), e_q = exp(q.k/8)
// Pass 1 (R18): loop-free, vectorized short8 loads, 3 shfl_xor dot-reduce,
// pad-swizzled LDS for v-partials.
__launch_bounds__(256)
__global__ void attn1(const ushort_t* __restrict__ qkv,
                      float* __restrict__ eG, float* __restrict__ psumG) {
  const int c = blockIdx.x & 63;
  const int i = (blockIdx.x >> 6) & 15;
  const int b = blockIdx.x >> 10;
  const int t = threadIdx.x;
  const int sg = t >> 3, h8 = (t & 7) * 8;
  const int s = c * 32 + sg;
  const size_t rb = (size_t)b * 2048 * 3072 + (size_t)s * 3072 + i * 64 + h8;
  short8 q8 = *(const short8*)(qkv + rb);
  short8 k8 = *(const short8*)(qkv + rb + 1024);
  short8 v8 = *(const short8*)(qkv + rb + 2048);
  float d = 0.f;
  float vf[8];
#pragma unroll
  for (int j = 0; j < 8; j++) {
    float qf = b2f((ushort_t)q8[j]);
    float kf = b2f((ushort_t)k8[j]);
    vf[j] = b2f((ushort_t)v8[j]);
    d += qf * kf;
  }
  d += __shfl_xor(d, 1, 64);
  d += __shfl_xor(d, 2, 64);
  d += __shfl_xor(d, 4, 64);
  if ((t & 7) == 0) eG[((size_t)(b * 16 + i)) * 2048 + s] = __expf(d * 0.125f);
  __shared__ float vs[32][68];  // +4 pad: b128 writes hit all 8 bank slots
#pragma unroll
  for (int j = 0; j < 8; j += 4)
    *(float4*)&vs[sg][h8 + j] = make_float4(vf[j], vf[j + 1], vf[j + 2], vf[j + 3]);
  __syncthreads();
  if (t < 64) {
    float acc = 0.f;
#pragma unroll 8
    for (int sgi = 0; sgi < 32; sgi++) acc += vs[sgi][t];
    psumG[(((size_t)(b * 16 + i)) * 64 + c) * 64 + t] = acc;
  }
}

// Pass 2 (R16): rcp hoisted off the serial chain; 4-acc suffix sum.
__launch_bounds__(256)
__global__ void attn2(const ushort_t* __restrict__ qkv,
                      const float* __restrict__ eG, const float* __restrict__ psumG,
                      ushort_t* __restrict__ Z) {
  const int wave = threadIdx.x >> 6, h = threadIdx.x & 63;
  const int c = (blockIdx.x & 15) * 4 + wave;
  const int i = (blockIdx.x >> 4) & 15;
  const int b = blockIdx.x >> 8;
  const size_t rowbase = (size_t)b * 2048 * 3072;
  const size_t pbase = ((size_t)(b * 16 + i)) * 64;
  float r0 = 0.f, r1 = 0.f, r2 = 0.f, r3 = 0.f;
  {
    int cc = c + 1;
    for (; cc + 3 < 64; cc += 4) {
      r0 += psumG[(pbase + cc) * 64 + h];
      r1 += psumG[(pbase + cc + 1) * 64 + h];
      r2 += psumG[(pbase + cc + 2) * 64 + h];
      r3 += psumG[(pbase + cc + 3) * 64 + h];
    }
    for (; cc < 64; cc++) r0 += psumG[(pbase + cc) * 64 + h];
  }
  float run = (r0 + r1) + (r2 + r3);
  const size_t ebase = ((size_t)(b * 16 + i)) * 2048;
  for (int t4 = 1; t4 >= 0; t4--) {
    float vv[16], num[16], rcp[16];
#pragma unroll
    for (int j = 0; j < 16; j++) {
      const int s = c * 32 + t4 * 16 + j;
      vv[j] = b2f(qkv[rowbase + (size_t)s * 3072 + 2048 + i * 64 + h]);
      float e = eG[ebase + s];
      num[j] = e * vv[j];
      float d = e + (float)(2047 - s);
      float r = __builtin_amdgcn_rcpf(d);
      rcp[j] = r * (2.f - d * r);  // one Newton step
    }
#pragma unroll
    for (int j = 15; j >= 0; j--) {
      const int s = c * 32 + t4 * 16 + j;
      float z = (num[j] + run) * rcp[j];
      Z[((size_t)b * 2048 + s) * 1024 + i * 64 + h] = f2b(z);
      run += vv[j];
    }
  }
}

// ---------------- launch ----------------------------------------------------
extern "C" void kernel_launch(void* const* d_in, const int* in_sizes, int n_in,
                              void* d_out, int out_size, void* d_ws, size_t ws_size,
                              hipStream_t stream) {
  const float* x     = (const float*)d_in[0];
  const float* W_Q   = (const float*)d_in[1];
  const float* W_K   = (const float*)d_in[2];
  const float* W_V   = (const float*)d_in[3];
  const float* W_O   = (const float*)d_in[4];
  const float* W_in  = (const float*)d_in[5];
  const float* b_in  = (const float*)d_in[6];
  const float* W_out = (const float*)d_in[7];
  const float* b_out = (const float*)d_in[8];
  float* out = (float*)d_out;

  // ws layout (max 104 MB).
  // P (32 MB) aliases [0,32): Xb/Wqkv/WOb/Z/QKV[0,8MB) all dead by MODE3
  // (stream-ordered). eG/psumG live inside Hb's region [72,104): consumed by
  // attn2 BEFORE MLP-in writes Hb, so no conflict.
  char* base = (char*)d_ws;
  const size_t MB = 1048576;
  ushort_t* Xb    = (ushort_t*)(base + 0 * MB);    // 8 MB
  ushort_t* Wqkv  = (ushort_t*)(base + 8 * MB);    // 6 MB
  ushort_t* WOb   = (ushort_t*)(base + 14 * MB);   // 2 MB
  ushort_t* Z     = (ushort_t*)(base + 16 * MB);   // 8 MB
  ushort_t* QKV   = (ushort_t*)(base + 24 * MB);   // 24 MB
  ushort_t* midb  = (ushort_t*)(base + 48 * MB);   // 8 MB
  ushort_t* Winb  = (ushort_t*)(base + 56 * MB);   // 8 MB
  ushort_t* Woutb = (ushort_t*)(base + 64 * MB);   // 8 MB
  ushort_t* Hb    = (ushort_t*)(base + 72 * MB);   // 32 MB
  float*    P     = (float*)(base + 0 * MB);       // 32 MB [0,32) alias
  float*    psumG = (float*)(base + 72 * MB);            // 512 KB (pre-MLP-in)
  float*    eG    = (float*)(base + 72 * MB + 524288);   // 256 KB (pre-MLP-in)

  Cvt7 ca;
  ca.src[0] = x;     ca.dst[0] = Xb;               ca.scale[0] = 1.f;
  ca.src[1] = W_Q;   ca.dst[1] = Wqkv;             ca.scale[1] = 1.f;
  ca.src[2] = W_K;   ca.dst[2] = Wqkv + 1048576;   ca.scale[2] = 1.f;
  ca.src[3] = W_V;   ca.dst[3] = Wqkv + 2097152;   ca.scale[3] = 1.f;
  ca.src[4] = W_O;   ca.dst[4] = WOb;              ca.scale[4] = 2.f;  // fold mid=2*attn_out
  ca.src[5] = W_in;  ca.dst[5] = Winb;             ca.scale[5] = 1.f;
  ca.src[6] = W_out; ca.dst[6] = Woutb;            ca.scale[6] = 1.f;
  unsigned n4s[7] = {1048576, 262144, 262144, 262144, 262144, 1048576, 1048576};
  unsigned acc4 = 0;
  for (int j = 0; j < 7; j++) { ca.start[j] = acc4; acc4 += n4s[j]; }
  ca.start[7] = acc4;
  cvt_all<<<dim3((acc4 + 255) / 256), dim3(256), 0, stream>>>(ca);

  // QKV = X * Wqkv^T [4096,3072]: gemm256 (measured 48.2 vs legacy 49.8).
  gemm256<0><<<dim3(12, 16), 512, 0, stream>>>(Xb, Wqkv, 4096, 3072, 1024, 1024,
                                               QKV, nullptr, nullptr);
  // attention -> Z [4096, 1024] bf16
  attn1<<<dim3(2048), 256, 0, stream>>>(QKV, eG, psumG);
  attn2<<<dim3(512), 256, 0, stream>>>(QKV, eG, psumG, Z);
  // mid = Z*(2*W_O)^T: legacy path, y-coloc (full B = 2 MB fits L2).
  gemm_bt<1, 2, 1><<<dim3(8, 64), 256, 0, stream>>>(Z, WOb, 4096, 1024, 1024, 1024,
                                                    midb, out, b_out);
  // H = relu(mid*W_in^T + b_in) [4096,4096]: gemm256 R11 (best measured).
  gemm256<2><<<dim3(16, 16), 512, 0, stream>>>(midb, Winb, 4096, 4096, 1024, 1024,
                                               Hb, nullptr, b_in);
  // P[z] = H slice * W_out^T: split-K=2, MT=2 cluster2 (best measured).
  gemm_bt<3, 2, 2><<<dim3(8, 64, 2), 256, 0, stream>>>(Hb, Woutb, 4096, 1024, 2048, 4096,
                                                       nullptr, P, nullptr);
  // out += P0 + P1
  reduce2<<<dim3(1024), 256, 0, stream>>>((const float4*)P, (float4*)out, 1048576);
}

// Round 14
// 279.145 us; speedup vs baseline: 1.0138x; 1.0138x over previous
//
#include <hip/hip_runtime.h>
#include <hip/hip_bf16.h>
#include <stdint.h>

typedef unsigned short ushort_t;
typedef __attribute__((ext_vector_type(8))) short short8;
typedef __attribute__((ext_vector_type(4))) float floatx4;

#define DEV __device__ __forceinline__

DEV ushort_t f2b(float f) {
  uint32_t x = __float_as_uint(f);
  uint32_t r = (x + 0x7FFFu + ((x >> 16) & 1u)) >> 16;
  return (ushort_t)r;
}
DEV float b2f(ushort_t u) { return __uint_as_float(((uint32_t)u) << 16); }

DEV void async16(const ushort_t* g, ushort_t* l) {
  __builtin_amdgcn_global_load_lds(
      (const __attribute__((address_space(1))) void*)g,
      (__attribute__((address_space(3))) void*)l, 16, 0, 0);
}

// ---------------- fused fp32 -> bf16 conversion (one launch) ----------------
struct Cvt7 {
  const float* src[7];
  ushort_t* dst[7];
  float scale[7];
  unsigned start[8];  // prefix, in float4 units
};
__global__ void cvt_all(Cvt7 a) {
  unsigned idx = blockIdx.x * blockDim.x + threadIdx.x;
  if (idx >= a.start[7]) return;
  int seg = 0;
#pragma unroll
  for (int j = 1; j < 7; j++) seg += (idx >= a.start[j]) ? 1 : 0;
  unsigned off = idx - a.start[seg];
  float sc = a.scale[seg];
  float4 v = ((const float4*)a.src[seg])[off];
  ((ushort4*)a.dst[seg])[off] =
      make_ushort4(f2b(v.x * sc), f2b(v.y * sc), f2b(v.z * sc), f2b(v.w * sc));
}

// ---------------- legacy 128-wide bf16 GEMM ---------------------------------
// C[M,N] = A[M,K=ldk]*B[N,ldk]^T. Tile (32*MT)x128, 256 thr, BK=64, 2-barrier.
// Session-final (best measured 279.3us). Closed trails:
//  - 6 K-loop schedules all ~26-27% MfmaUtil at K=1024 (2-phase ceiling).
//  - MLP-out: split2+reduce2 < atomic < non-split < MT=4/SWZ0 (A-locality).
//  - Traffic shuffling between stream-ordered kernels: 3x null.
//  - Occupancy escape VGPR-infeasible (64x64 wave tile needs ~130 VGPR).
// MODE 1: outB = bf16(acc); outF = acc + bias   (mid; WOb pre-scaled x2)
// MODE 3: outF[z*M*N+idx] = acc                 (MLP-out split-K partials)
template <int MODE, int MT, int SWZ>
__launch_bounds__(256)
__global__ void gemm_bt(const ushort_t* __restrict__ A, const ushort_t* __restrict__ Bm,
                        int M, int N, int Kd, int ldk,
                        ushort_t* __restrict__ outB, float* __restrict__ outF,
                        const float* __restrict__ bias) {
  constexpr int TM = 32 * MT;
  __shared__ alignas(16) ushort_t As[TM * 64];
  __shared__ alignas(16) ushort_t Bs[128 * 64];
  const int tid = threadIdx.x;
  const int wave = tid >> 6, lane = tid & 63;
  const int wm = wave >> 1, wn = wave & 1;

  int bx, by;
  if constexpr (SWZ == 1) {
    const int f = blockIdx.x + gridDim.x * blockIdx.y;
    by = (f & 7) + 8 * (f / (8 * gridDim.x));
    bx = (f >> 3) % gridDim.x;
  } else if constexpr (SWZ == 2) {
    const int x = blockIdx.x, y = blockIdx.y;  // gx=8: XCD = x
    bx = 2 * (x & 3) + (y & 1);
    by = (y >> 1) + 32 * (x >> 2);
  } else {
    bx = blockIdx.x; by = blockIdx.y;
  }
  const int m0 = by * TM, n0 = bx * 128;
  const int kz = blockIdx.z * Kd;

  floatx4 acc[MT][4];
#pragma unroll
  for (int i = 0; i < MT; i++)
#pragma unroll
    for (int j = 0; j < 4; j++) acc[i][j] = (floatx4){0.f, 0.f, 0.f, 0.f};

  const int r8 = lane >> 3;
  const int scol = (((lane & 7) ^ (r8 & 7)) * 8);
  const ushort_t* gA = A + (size_t)(m0 + wave * (TM / 4) + r8) * ldk + kz + scol;
  const ushort_t* gB = Bm + (size_t)(n0 + wave * 32 + r8) * ldk + kz + scol;
  ushort_t* lA = As + wave * (TM / 4) * 64;
  ushort_t* lB = Bs + wave * 2048;

  const int fr = lane & 15, fq = lane >> 4;
  const int sw = fr & 7;
  const ushort_t* rdA = As + (wm * 16 * MT + fr) * 64;
  const ushort_t* rdB = Bs + (wn * 64 + fr) * 64;

  for (int k0 = 0; k0 < Kd; k0 += 64) {
#pragma unroll
    for (int j = 0; j < MT; j++) async16(gA + (size_t)j * 8 * ldk, lA + j * 512);
#pragma unroll
    for (int j = 0; j < 4; j++) async16(gB + (size_t)j * 8 * ldk, lB + j * 512);
    gA += 64; gB += 64;
    __syncthreads();
#pragma unroll
    for (int h = 0; h < 2; h++) {
      const int co = ((h * 4 + fq) ^ sw) * 8;
      short8 af[MT], bfv[4];
#pragma unroll
      for (int mt = 0; mt < MT; mt++) af[mt] = *(const short8*)(rdA + mt * 16 * 64 + co);
#pragma unroll
      for (int nt = 0; nt < 4; nt++) bfv[nt] = *(const short8*)(rdB + nt * 16 * 64 + co);
#pragma unroll
      for (int mt = 0; mt < MT; mt++)
#pragma unroll
        for (int nt = 0; nt < 4; nt++)
          acc[mt][nt] = __builtin_amdgcn_mfma_f32_16x16x32_bf16(af[mt], bfv[nt], acc[mt][nt], 0, 0, 0);
    }
    __syncthreads();
  }

  const int crow = m0 + wm * 16 * MT + (lane >> 4) * 4;
  const int ccol = n0 + wn * 64 + (lane & 15);
  const size_t zoff = (size_t)blockIdx.z * M * N;
#pragma unroll
  for (int mt = 0; mt < MT; mt++)
#pragma unroll
    for (int nt = 0; nt < 4; nt++) {
      floatx4 a = acc[mt][nt];
#pragma unroll
      for (int r = 0; r < 4; r++) {
        const int gm = crow + mt * 16 + r;
        const int gn = ccol + nt * 16;
        const size_t idx = (size_t)gm * N + gn;
        float v = a[r];
        if constexpr (MODE == 0) {
          outB[idx] = f2b(v);
        } else if constexpr (MODE == 1) {
          outB[idx] = f2b(v);          // WOb pre-scaled by 2 in cvt
          outF[idx] = v + bias[gn];
        } else if constexpr (MODE == 2) {
          float t = v + bias[gn];
          outB[idx] = f2b(t > 0.f ? t : 0.f);
        } else {
          outF[zoff + idx] = v;
        }
      }
    }
}

// ---------------- 256x256 pipelined bf16 GEMM (R11 schedule) ----------------
// Best measured for QKV (48.2us) and MLP-in (46-48us). 128KB LDS.
// MODE 0: bf16(acc)   MODE 2: bf16(relu(acc+bias))
template <int MODE>
__launch_bounds__(512, 2)
__global__ void gemm256(const ushort_t* __restrict__ A, const ushort_t* __restrict__ Bm,
                        int M, int N, int Kd, int ldk,
                        ushort_t* __restrict__ outB, float* __restrict__ outF,
                        const float* __restrict__ bias) {
  __shared__ alignas(16) ushort_t As[4][256 * 32];
  __shared__ alignas(16) ushort_t Bs[4][256 * 32];
  const int tid = threadIdx.x;
  const int lane = tid & 63;
  const int wave = tid >> 6;
  const int wm = wave >> 2, wn = wave & 3;

  // bijective XCD-chunk swizzle on the flat (x,y) id (m204 form).
  const int gy = gridDim.y;
  int f = blockIdx.x + gridDim.x * blockIdx.y;
  {
    const int nwg = gridDim.x * gy;
    const int q = nwg >> 3, rr = nwg & 7;
    const int xcd = f & 7, ix = f >> 3;
    f = (xcd < rr ? xcd * (q + 1) : rr * (q + 1) + (xcd - rr) * q) + ix;
  }
  const int bx = f / gy, by = f - gy * bx;
  const int m0 = by * 256, n0 = bx * 256;
  const size_t kz = (size_t)blockIdx.z * Kd;

  floatx4 acc[8][4];
#pragma unroll
  for (int i = 0; i < 8; i++)
#pragma unroll
    for (int j = 0; j < 4; j++) acc[i][j] = (floatx4){0.f, 0.f, 0.f, 0.f};

  const int rloc = tid >> 2, cch = tid & 3;
  const int gcol = ((cch ^ ((rloc >> 1) & 3)) * 8);
  const ushort_t* gA = A + (size_t)(m0 + rloc) * ldk + kz + gcol;
  const ushort_t* gB = Bm + (size_t)(n0 + rloc) * ldk + kz + gcol;
  const int lofs = rloc * 32 + cch * 8;

#define STGA32(bufi, kofs)                                              \
  {                                                                     \
    async16(gA + (kofs), &As[bufi][lofs]);                              \
    async16(gA + (size_t)128 * ldk + (kofs), &As[bufi][4096 + lofs]);   \
  }
#define STGB32(bufi, kofs)                                              \
  {                                                                     \
    async16(gB + (kofs), &Bs[bufi][lofs]);                              \
    async16(gB + (size_t)128 * ldk + (kofs), &Bs[bufi][4096 + lofs]);   \
  }

  const int NT = Kd >> 5;  // K-tiles of 32
  STGA32(0, 0) STGB32(0, 0)
  if (NT > 1) { STGA32(1, 32) STGB32(1, 32) }
  if (NT > 2) { STGA32(2, 64) STGB32(2, 64) }
  if (NT > 2) asm volatile("s_waitcnt vmcnt(8)" ::: "memory");
  else if (NT > 1) asm volatile("s_waitcnt vmcnt(4)" ::: "memory");
  else asm volatile("s_waitcnt vmcnt(0)" ::: "memory");
  __builtin_amdgcn_s_barrier();

  const int fr = lane & 15, fq = lane >> 4;
  const int co = ((fq ^ ((fr >> 1) & 3)) * 8);
  const int aoff = (wm * 128 + fr) * 32 + co;
  const int boff = (wn * 64 + fr) * 32 + co;

  for (int kt = 0; kt < NT; ++kt) {
    const int cb = kt & 3;            // compute slot
    const int pb = (kt + 3) & 3;      // prefetch slot (== (kt-1)&3, freed)
    const int kof = (kt + 3) * 32;
    const bool sp = (kt + 3) < NT;
    const ushort_t* Ab = As[cb];
    const ushort_t* Bb = Bs[cb];
    short8 av[4], bv[4];

    // ---- phase 0: QM=0 (rows wm*128..+64), all 4 n-frags ----
#pragma unroll
    for (int i = 0; i < 4; i++) av[i] = *(const short8*)(Ab + aoff + i * 512);
#pragma unroll
    for (int j = 0; j < 4; j++) bv[j] = *(const short8*)(Bb + boff + j * 512);
    if (sp) STGA32(pb, kof)
    __builtin_amdgcn_s_barrier();
    asm volatile("s_waitcnt lgkmcnt(0)" ::: "memory");
    __builtin_amdgcn_s_setprio(1);
#pragma unroll
    for (int i = 0; i < 4; i++)
#pragma unroll
      for (int j = 0; j < 4; j++)
        acc[i][j] = __builtin_amdgcn_mfma_f32_16x16x32_bf16(av[i], bv[j], acc[i][j], 0, 0, 0);
    __builtin_amdgcn_s_setprio(0);
    __builtin_amdgcn_s_barrier();

    // ---- phase 1: QM=1 (rows wm*128+64..+64), reuse bv ----
#pragma unroll
    for (int i = 0; i < 4; i++) av[i] = *(const short8*)(Ab + aoff + 2048 + i * 512);
    if (sp) STGB32(pb, kof)
    __builtin_amdgcn_s_barrier();
    asm volatile("s_waitcnt lgkmcnt(0)" ::: "memory");
    __builtin_amdgcn_s_setprio(1);
#pragma unroll
    for (int i = 0; i < 4; i++)
#pragma unroll
      for (int j = 0; j < 4; j++)
        acc[4 + i][j] = __builtin_amdgcn_mfma_f32_16x16x32_bf16(av[i], bv[j], acc[4 + i][j], 0, 0, 0);
    __builtin_amdgcn_s_setprio(0);
    if (kt + 3 < NT) asm volatile("s_waitcnt vmcnt(8)" ::: "memory");
    else if (kt + 2 < NT) asm volatile("s_waitcnt vmcnt(4)" ::: "memory");
    else asm volatile("s_waitcnt vmcnt(0)" ::: "memory");
    __builtin_amdgcn_s_barrier();
  }
#undef STGA32
#undef STGB32

  const int crow = m0 + wm * 128 + (lane >> 4) * 4;
  const int ccol = n0 + wn * 64 + (lane & 15);
#pragma unroll
  for (int mt = 0; mt < 8; mt++)
#pragma unroll
    for (int nt = 0; nt < 4; nt++) {
      floatx4 a = acc[mt][nt];
#pragma unroll
      for (int r = 0; r < 4; r++) {
        const int gm = crow + mt * 16 + r;
        const int gn = ccol + nt * 16;
        const size_t idx = (size_t)gm * N + gn;
        if constexpr (MODE == 0) {
          outB[idx] = f2b(a[r]);
        } else if constexpr (MODE == 2) {
          float t = a[r] + bias[gn];
          outB[idx] = f2b(t > 0.f ? t : 0.f);
        } else {
          outF[idx] = a[r];
        }
      }
    }
}

// ---------------- split-K=2 reduction: out += P0 + P1 -----------------------
__launch_bounds__(256)
__global__ void reduce2(const float4* __restrict__ P, float4* __restrict__ out, int n4) {
  int i = blockIdx.x * blockDim.x + threadIdx.x;
  int st = gridDim.x * blockDim.x;
  for (; i < n4; i += st) {
    float4 a = out[i];
    float4 p0 = P[i], p1 = P[i + 1048576];
    a.x += p0.x + p1.x;
    a.y += p0.y + p1.y;
    a.z += p0.z + p1.z;
    a.w += p0.w + p1.w;
    out[i] = a;
  }
}

// ---------------- attention (degenerate mask -> diag + suffix sum) ----------
// z[q] = (e_q*v[q] + sum_{p>q} v[p]) / (e_q + (S-1-q)), e_q = exp(q.k/8)
// Pass 1 (R18): loop-free, vectorized short8 loads, 3 shfl_xor dot-reduce,
// pad-swizzled LDS for v-partials.
__launch_bounds__(256)
__global__ void attn1(const ushort_t* __restrict__ qkv,
                      float* __restrict__ eG, float* __restrict__ psumG) {
  const int c = blockIdx.x & 63;
  const int i = (blockIdx.x >> 6) & 15;
  const int b = blockIdx.x >> 10;
  const int t = threadIdx.x;
  const int sg = t >> 3, h8 = (t & 7) * 8;
  const int s = c * 32 + sg;
  const size_t rb = (size_t)b * 2048 * 3072 + (size_t)s * 3072 + i * 64 + h8;
  short8 q8 = *(const short8*)(qkv + rb);
  short8 k8 = *(const short8*)(qkv + rb + 1024);
  short8 v8 = *(const short8*)(qkv + rb + 2048);
  float d = 0.f;
  float vf[8];
#pragma unroll
  for (int j = 0; j < 8; j++) {
    float qf = b2f((ushort_t)q8[j]);
    float kf = b2f((ushort_t)k8[j]);
    vf[j] = b2f((ushort_t)v8[j]);
    d += qf * kf;
  }
  d += __shfl_xor(d, 1, 64);
  d += __shfl_xor(d, 2, 64);
  d += __shfl_xor(d, 4, 64);
  if ((t & 7) == 0) eG[((size_t)(b * 16 + i)) * 2048 + s] = __expf(d * 0.125f);
  __shared__ float vs[32][68];  // +4 pad: b128 writes hit all 8 bank slots
#pragma unroll
  for (int j = 0; j < 8; j += 4)
    *(float4*)&vs[sg][h8 + j] = make_float4(vf[j], vf[j + 1], vf[j + 2], vf[j + 3]);
  __syncthreads();
  if (t < 64) {
    float acc = 0.f;
#pragma unroll 8
    for (int sgi = 0; sgi < 32; sgi++) acc += vs[sgi][t];
    psumG[(((size_t)(b * 16 + i)) * 64 + c) * 64 + t] = acc;
  }
}

// Pass 2 (R16): rcp hoisted off the serial chain; 4-acc suffix sum.
__launch_bounds__(256)
__global__ void attn2(const ushort_t* __restrict__ qkv,
                      const float* __restrict__ eG, const float* __restrict__ psumG,
                      ushort_t* __restrict__ Z) {
  const int wave = threadIdx.x >> 6, h = threadIdx.x & 63;
  const int c = (blockIdx.x & 15) * 4 + wave;
  const int i = (blockIdx.x >> 4) & 15;
  const int b = blockIdx.x >> 8;
  const size_t rowbase = (size_t)b * 2048 * 3072;
  const size_t pbase = ((size_t)(b * 16 + i)) * 64;
  float r0 = 0.f, r1 = 0.f, r2 = 0.f, r3 = 0.f;
  {
    int cc = c + 1;
    for (; cc + 3 < 64; cc += 4) {
      r0 += psumG[(pbase + cc) * 64 + h];
      r1 += psumG[(pbase + cc + 1) * 64 + h];
      r2 += psumG[(pbase + cc + 2) * 64 + h];
      r3 += psumG[(pbase + cc + 3) * 64 + h];
    }
    for (; cc < 64; cc++) r0 += psumG[(pbase + cc) * 64 + h];
  }
  float run = (r0 + r1) + (r2 + r3);
  const size_t ebase = ((size_t)(b * 16 + i)) * 2048;
  for (int t4 = 1; t4 >= 0; t4--) {
    float vv[16], num[16], rcp[16];
#pragma unroll
    for (int j = 0; j < 16; j++) {
      const int s = c * 32 + t4 * 16 + j;
      vv[j] = b2f(qkv[rowbase + (size_t)s * 3072 + 2048 + i * 64 + h]);
      float e = eG[ebase + s];
      num[j] = e * vv[j];
      float d = e + (float)(2047 - s);
      float r = __builtin_amdgcn_rcpf(d);
      rcp[j] = r * (2.f - d * r);  // one Newton step
    }
#pragma unroll
    for (int j = 15; j >= 0; j--) {
      const int s = c * 32 + t4 * 16 + j;
      float z = (num[j] + run) * rcp[j];
      Z[((size_t)b * 2048 + s) * 1024 + i * 64 + h] = f2b(z);
      run += vv[j];
    }
  }
}

// ---------------- launch ----------------------------------------------------
extern "C" void kernel_launch(void* const* d_in, const int* in_sizes, int n_in,
                              void* d_out, int out_size, void* d_ws, size_t ws_size,
                              hipStream_t stream) {
  const float* x     = (const float*)d_in[0];
  const float* W_Q   = (const float*)d_in[1];
  const float* W_K   = (const float*)d_in[2];
  const float* W_V   = (const float*)d_in[3];
  const float* W_O   = (const float*)d_in[4];
  const float* W_in  = (const float*)d_in[5];
  const float* b_in  = (const float*)d_in[6];
  const float* W_out = (const float*)d_in[7];
  const float* b_out = (const float*)d_in[8];
  float* out = (float*)d_out;

  // ws layout (max 104 MB).
  // P (32 MB) aliases [0,32): Xb/Wqkv/WOb/Z/QKV[0,8MB) all dead by MODE3
  // (stream-ordered). eG/psumG live inside Hb's region [72,104): consumed by
  // attn2 BEFORE MLP-in writes Hb, so no conflict.
  char* base = (char*)d_ws;
  const size_t MB = 1048576;
  ushort_t* Xb    = (ushort_t*)(base + 0 * MB);    // 8 MB
  ushort_t* Wqkv  = (ushort_t*)(base + 8 * MB);    // 6 MB
  ushort_t* WOb   = (ushort_t*)(base + 14 * MB);   // 2 MB
  ushort_t* Z     = (ushort_t*)(base + 16 * MB);   // 8 MB
  ushort_t* QKV   = (ushort_t*)(base + 24 * MB);   // 24 MB
  ushort_t* midb  = (ushort_t*)(base + 48 * MB);   // 8 MB
  ushort_t* Winb  = (ushort_t*)(base + 56 * MB);   // 8 MB
  ushort_t* Woutb = (ushort_t*)(base + 64 * MB);   // 8 MB
  ushort_t* Hb    = (ushort_t*)(base + 72 * MB);   // 32 MB
  float*    P     = (float*)(base + 0 * MB);       // 32 MB [0,32) alias
  float*    psumG = (float*)(base + 72 * MB);            // 512 KB (pre-MLP-in)
  float*    eG    = (float*)(base + 72 * MB + 524288);   // 256 KB (pre-MLP-in)

  Cvt7 ca;
  ca.src[0] = x;     ca.dst[0] = Xb;               ca.scale[0] = 1.f;
  ca.src[1] = W_Q;   ca.dst[1] = Wqkv;             ca.scale[1] = 1.f;
  ca.src[2] = W_K;   ca.dst[2] = Wqkv + 1048576;   ca.scale[2] = 1.f;
  ca.src[3] = W_V;   ca.dst[3] = Wqkv + 2097152;   ca.scale[3] = 1.f;
  ca.src[4] = W_O;   ca.dst[4] = WOb;              ca.scale[4] = 2.f;  // fold mid=2*attn_out
  ca.src[5] = W_in;  ca.dst[5] = Winb;             ca.scale[5] = 1.f;
  ca.src[6] = W_out; ca.dst[6] = Woutb;            ca.scale[6] = 1.f;
  unsigned n4s[7] = {1048576, 262144, 262144, 262144, 262144, 1048576, 1048576};
  unsigned acc4 = 0;
  for (int j = 0; j < 7; j++) { ca.start[j] = acc4; acc4 += n4s[j]; }
  ca.start[7] = acc4;
  cvt_all<<<dim3((acc4 + 255) / 256), dim3(256), 0, stream>>>(ca);

  // QKV = X * Wqkv^T [4096,3072]: gemm256 (measured 48.2 vs legacy 49.8).
  gemm256<0><<<dim3(12, 16), 512, 0, stream>>>(Xb, Wqkv, 4096, 3072, 1024, 1024,
                                               QKV, nullptr, nullptr);
  // attention -> Z [4096, 1024] bf16
  attn1<<<dim3(2048), 256, 0, stream>>>(QKV, eG, psumG);
  attn2<<<dim3(512), 256, 0, stream>>>(QKV, eG, psumG, Z);
  // mid = Z*(2*W_O)^T: legacy path, y-coloc (full B = 2 MB fits L2).
  gemm_bt<1, 2, 1><<<dim3(8, 64), 256, 0, stream>>>(Z, WOb, 4096, 1024, 1024, 1024,
                                                    midb, out, b_out);
  // H = relu(mid*W_in^T + b_in) [4096,4096]: gemm256 R11 (best measured).
  gemm256<2><<<dim3(16, 16), 512, 0, stream>>>(midb, Winb, 4096, 4096, 1024, 1024,
                                               Hb, nullptr, b_in);
  // P[z] = H slice * W_out^T: split-K=2, MT=2 cluster2 (best measured).
  gemm_bt<3, 2, 2><<<dim3(8, 64, 2), 256, 0, stream>>>(Hb, Woutb, 4096, 1024, 2048, 4096,
                                                       nullptr, P, nullptr);
  // out += P0 + P1
  reduce2<<<dim3(1024), 256, 0, stream>>>((const float4*)P, (float4*)out, 1048576);
}

// Round 15
// 274.740 us; speedup vs baseline: 1.0300x; 1.0160x over previous
//
#include <hip/hip_runtime.h>
#include <hip/hip_bf16.h>
#include <stdint.h>

typedef unsigned short ushort_t;
typedef __attribute__((ext_vector_type(8))) short short8;
typedef __attribute__((ext_vector_type(4))) float floatx4;

#define DEV __device__ __forceinline__

DEV ushort_t f2b(float f) {
  uint32_t x = __float_as_uint(f);
  uint32_t r = (x + 0x7FFFu + ((x >> 16) & 1u)) >> 16;
  return (ushort_t)r;
}
DEV float b2f(ushort_t u) { return __uint_as_float(((uint32_t)u) << 16); }

DEV void async16(const ushort_t* g, ushort_t* l) {
  __builtin_amdgcn_global_load_lds(
      (const __attribute__((address_space(1))) void*)g,
      (__attribute__((address_space(3))) void*)l, 16, 0, 0);
}

// ---------------- fused fp32 -> bf16 conversion (one launch) ----------------
struct Cvt7 {
  const float* src[7];
  ushort_t* dst[7];
  float scale[7];
  unsigned start[8];  // prefix, in float4 units
};
__global__ void cvt_all(Cvt7 a) {
  unsigned idx = blockIdx.x * blockDim.x + threadIdx.x;
  if (idx >= a.start[7]) return;
  int seg = 0;
#pragma unroll
  for (int j = 1; j < 7; j++) seg += (idx >= a.start[j]) ? 1 : 0;
  unsigned off = idx - a.start[seg];
  float sc = a.scale[seg];
  float4 v = ((const float4*)a.src[seg])[off];
  ((ushort4*)a.dst[seg])[off] =
      make_ushort4(f2b(v.x * sc), f2b(v.y * sc), f2b(v.z * sc), f2b(v.w * sc));
}

// ---------------- legacy 128-wide bf16 GEMM ---------------------------------
// C[M,N] = A[M,K=ldk]*B[N,ldk]^T. Tile (32*MT)x128, 256 thr, BK=64, 2-barrier.
// MODE 1: outB = bf16(acc); outF = acc + bias   (mid; WOb pre-scaled x2)
// MODE 3: outF[z*M*N+idx] = acc                 (MLP-out split-K partials)
template <int MODE, int MT, int SWZ>
__launch_bounds__(256)
__global__ void gemm_bt(const ushort_t* __restrict__ A, const ushort_t* __restrict__ Bm,
                        int M, int N, int Kd, int ldk,
                        ushort_t* __restrict__ outB, float* __restrict__ outF,
                        const float* __restrict__ bias) {
  constexpr int TM = 32 * MT;
  __shared__ alignas(16) ushort_t As[TM * 64];
  __shared__ alignas(16) ushort_t Bs[128 * 64];
  const int tid = threadIdx.x;
  const int wave = tid >> 6, lane = tid & 63;
  const int wm = wave >> 1, wn = wave & 1;

  int bx, by;
  if constexpr (SWZ == 1) {
    const int f = blockIdx.x + gridDim.x * blockIdx.y;
    by = (f & 7) + 8 * (f / (8 * gridDim.x));
    bx = (f >> 3) % gridDim.x;
  } else if constexpr (SWZ == 2) {
    const int x = blockIdx.x, y = blockIdx.y;  // gx=8: XCD = x
    bx = 2 * (x & 3) + (y & 1);
    by = (y >> 1) + 32 * (x >> 2);
  } else {
    bx = blockIdx.x; by = blockIdx.y;
  }
  const int m0 = by * TM, n0 = bx * 128;
  const int kz = blockIdx.z * Kd;

  floatx4 acc[MT][4];
#pragma unroll
  for (int i = 0; i < MT; i++)
#pragma unroll
    for (int j = 0; j < 4; j++) acc[i][j] = (floatx4){0.f, 0.f, 0.f, 0.f};

  const int r8 = lane >> 3;
  const int scol = (((lane & 7) ^ (r8 & 7)) * 8);
  const ushort_t* gA = A + (size_t)(m0 + wave * (TM / 4) + r8) * ldk + kz + scol;
  const ushort_t* gB = Bm + (size_t)(n0 + wave * 32 + r8) * ldk + kz + scol;
  ushort_t* lA = As + wave * (TM / 4) * 64;
  ushort_t* lB = Bs + wave * 2048;

  const int fr = lane & 15, fq = lane >> 4;
  const int sw = fr & 7;
  const ushort_t* rdA = As + (wm * 16 * MT + fr) * 64;
  const ushort_t* rdB = Bs + (wn * 64 + fr) * 64;

  for (int k0 = 0; k0 < Kd; k0 += 64) {
#pragma unroll
    for (int j = 0; j < MT; j++) async16(gA + (size_t)j * 8 * ldk, lA + j * 512);
#pragma unroll
    for (int j = 0; j < 4; j++) async16(gB + (size_t)j * 8 * ldk, lB + j * 512);
    gA += 64; gB += 64;
    __syncthreads();
#pragma unroll
    for (int h = 0; h < 2; h++) {
      const int co = ((h * 4 + fq) ^ sw) * 8;
      short8 af[MT], bfv[4];
#pragma unroll
      for (int mt = 0; mt < MT; mt++) af[mt] = *(const short8*)(rdA + mt * 16 * 64 + co);
#pragma unroll
      for (int nt = 0; nt < 4; nt++) bfv[nt] = *(const short8*)(rdB + nt * 16 * 64 + co);
#pragma unroll
      for (int mt = 0; mt < MT; mt++)
#pragma unroll
        for (int nt = 0; nt < 4; nt++)
          acc[mt][nt] = __builtin_amdgcn_mfma_f32_16x16x32_bf16(af[mt], bfv[nt], acc[mt][nt], 0, 0, 0);
    }
    __syncthreads();
  }

  const int crow = m0 + wm * 16 * MT + (lane >> 4) * 4;
  const int ccol = n0 + wn * 64 + (lane & 15);
  const size_t zoff = (size_t)blockIdx.z * M * N;
#pragma unroll
  for (int mt = 0; mt < MT; mt++)
#pragma unroll
    for (int nt = 0; nt < 4; nt++) {
      floatx4 a = acc[mt][nt];
#pragma unroll
      for (int r = 0; r < 4; r++) {
        const int gm = crow + mt * 16 + r;
        const int gn = ccol + nt * 16;
        const size_t idx = (size_t)gm * N + gn;
        float v = a[r];
        if constexpr (MODE == 0) {
          outB[idx] = f2b(v);
        } else if constexpr (MODE == 1) {
          outB[idx] = f2b(v);          // WOb pre-scaled by 2 in cvt
          outF[idx] = v + bias[gn];
        } else if constexpr (MODE == 2) {
          float t = v + bias[gn];
          outB[idx] = f2b(t > 0.f ? t : 0.f);
        } else {
          outF[zoff + idx] = v;
        }
      }
    }
}

// ---------------- 256x256 pipelined bf16 GEMM (R11 schedule) ----------------
// Best measured for MLP-in (46-48us). 128KB LDS, 1 block/CU.
// MODE 2: bf16(relu(acc+bias))
template <int MODE>
__launch_bounds__(512, 2)
__global__ void gemm256(const ushort_t* __restrict__ A, const ushort_t* __restrict__ Bm,
                        int M, int N, int Kd, int ldk,
                        ushort_t* __restrict__ outB, float* __restrict__ outF,
                        const float* __restrict__ bias) {
  __shared__ alignas(16) ushort_t As[4][256 * 32];
  __shared__ alignas(16) ushort_t Bs[4][256 * 32];
  const int tid = threadIdx.x;
  const int lane = tid & 63;
  const int wave = tid >> 6;
  const int wm = wave >> 2, wn = wave & 3;

  // bijective XCD-chunk swizzle on the flat (x,y) id (m204 form).
  const int gy = gridDim.y;
  int f = blockIdx.x + gridDim.x * blockIdx.y;
  {
    const int nwg = gridDim.x * gy;
    const int q = nwg >> 3, rr = nwg & 7;
    const int xcd = f & 7, ix = f >> 3;
    f = (xcd < rr ? xcd * (q + 1) : rr * (q + 1) + (xcd - rr) * q) + ix;
  }
  const int bx = f / gy, by = f - gy * bx;
  const int m0 = by * 256, n0 = bx * 256;
  const size_t kz = (size_t)blockIdx.z * Kd;

  floatx4 acc[8][4];
#pragma unroll
  for (int i = 0; i < 8; i++)
#pragma unroll
    for (int j = 0; j < 4; j++) acc[i][j] = (floatx4){0.f, 0.f, 0.f, 0.f};

  const int rloc = tid >> 2, cch = tid & 3;
  const int gcol = ((cch ^ ((rloc >> 1) & 3)) * 8);
  const ushort_t* gA = A + (size_t)(m0 + rloc) * ldk + kz + gcol;
  const ushort_t* gB = Bm + (size_t)(n0 + rloc) * ldk + kz + gcol;
  const int lofs = rloc * 32 + cch * 8;

#define STGA32(bufi, kofs)                                              \
  {                                                                     \
    async16(gA + (kofs), &As[bufi][lofs]);                              \
    async16(gA + (size_t)128 * ldk + (kofs), &As[bufi][4096 + lofs]);   \
  }
#define STGB32(bufi, kofs)                                              \
  {                                                                     \
    async16(gB + (kofs), &Bs[bufi][lofs]);                              \
    async16(gB + (size_t)128 * ldk + (kofs), &Bs[bufi][4096 + lofs]);   \
  }

  const int NT = Kd >> 5;  // K-tiles of 32
  STGA32(0, 0) STGB32(0, 0)
  if (NT > 1) { STGA32(1, 32) STGB32(1, 32) }
  if (NT > 2) { STGA32(2, 64) STGB32(2, 64) }
  if (NT > 2) asm volatile("s_waitcnt vmcnt(8)" ::: "memory");
  else if (NT > 1) asm volatile("s_waitcnt vmcnt(4)" ::: "memory");
  else asm volatile("s_waitcnt vmcnt(0)" ::: "memory");
  __builtin_amdgcn_s_barrier();

  const int fr = lane & 15, fq = lane >> 4;
  const int co = ((fq ^ ((fr >> 1) & 3)) * 8);
  const int aoff = (wm * 128 + fr) * 32 + co;
  const int boff = (wn * 64 + fr) * 32 + co;

  for (int kt = 0; kt < NT; ++kt) {
    const int cb = kt & 3;            // compute slot
    const int pb = (kt + 3) & 3;      // prefetch slot (== (kt-1)&3, freed)
    const int kof = (kt + 3) * 32;
    const bool sp = (kt + 3) < NT;
    const ushort_t* Ab = As[cb];
    const ushort_t* Bb = Bs[cb];
    short8 av[4], bv[4];

    // ---- phase 0: QM=0 (rows wm*128..+64), all 4 n-frags ----
#pragma unroll
    for (int i = 0; i < 4; i++) av[i] = *(const short8*)(Ab + aoff + i * 512);
#pragma unroll
    for (int j = 0; j < 4; j++) bv[j] = *(const short8*)(Bb + boff + j * 512);
    if (sp) STGA32(pb, kof)
    __builtin_amdgcn_s_barrier();
    asm volatile("s_waitcnt lgkmcnt(0)" ::: "memory");
    __builtin_amdgcn_s_setprio(1);
#pragma unroll
    for (int i = 0; i < 4; i++)
#pragma unroll
      for (int j = 0; j < 4; j++)
        acc[i][j] = __builtin_amdgcn_mfma_f32_16x16x32_bf16(av[i], bv[j], acc[i][j], 0, 0, 0);
    __builtin_amdgcn_s_setprio(0);
    __builtin_amdgcn_s_barrier();

    // ---- phase 1: QM=1 (rows wm*128+64..+64), reuse bv ----
#pragma unroll
    for (int i = 0; i < 4; i++) av[i] = *(const short8*)(Ab + aoff + 2048 + i * 512);
    if (sp) STGB32(pb, kof)
    __builtin_amdgcn_s_barrier();
    asm volatile("s_waitcnt lgkmcnt(0)" ::: "memory");
    __builtin_amdgcn_s_setprio(1);
#pragma unroll
    for (int i = 0; i < 4; i++)
#pragma unroll
      for (int j = 0; j < 4; j++)
        acc[4 + i][j] = __builtin_amdgcn_mfma_f32_16x16x32_bf16(av[i], bv[j], acc[4 + i][j], 0, 0, 0);
    __builtin_amdgcn_s_setprio(0);
    if (kt + 3 < NT) asm volatile("s_waitcnt vmcnt(8)" ::: "memory");
    else if (kt + 2 < NT) asm volatile("s_waitcnt vmcnt(4)" ::: "memory");
    else asm volatile("s_waitcnt vmcnt(0)" ::: "memory");
    __builtin_amdgcn_s_barrier();
  }
#undef STGA32
#undef STGB32

  const int crow = m0 + wm * 128 + (lane >> 4) * 4;
  const int ccol = n0 + wn * 64 + (lane & 15);
#pragma unroll
  for (int mt = 0; mt < 8; mt++)
#pragma unroll
    for (int nt = 0; nt < 4; nt++) {
      floatx4 a = acc[mt][nt];
#pragma unroll
      for (int r = 0; r < 4; r++) {
        const int gm = crow + mt * 16 + r;
        const int gn = ccol + nt * 16;
        const size_t idx = (size_t)gm * N + gn;
        if constexpr (MODE == 0) {
          outB[idx] = f2b(a[r]);
        } else if constexpr (MODE == 2) {
          float t = a[r] + bias[gn];
          outB[idx] = f2b(t > 0.f ? t : 0.f);
        } else {
          outF[idx] = a[r];
        }
      }
    }
}

// ---------------- 256x192 pipelined bf16 GEMM (R24, QKV) --------------------
// Same R11 schedule/sync as gemm256; tile narrowed to 256x192 so the QKV
// grid becomes 16x16 = 256 blocks (full CU coverage; was 192 blocks with
// 64 CUs idle). Per-block MFMA work x0.75, B-staging bytes x0.75; sync
// structure IDENTICAL (4 loads/tile/wave: B's 192 rows staged as two full
// 128-row calls at row offsets 0 and 64 -> rows 64..127 written twice with
// identical bytes, benign). K-order per acc unchanged -> bitwise-same QKV.
// LDS: A 64KB + B 48KB = 112 KB.
template <int MODE>
__launch_bounds__(512, 2)
__global__ void gemm192(const ushort_t* __restrict__ A, const ushort_t* __restrict__ Bm,
                        int M, int N, int Kd, int ldk,
                        ushort_t* __restrict__ outB, float* __restrict__ outF,
                        const float* __restrict__ bias) {
  __shared__ alignas(16) ushort_t As[4][256 * 32];
  __shared__ alignas(16) ushort_t Bs[4][192 * 32];
  const int tid = threadIdx.x;
  const int lane = tid & 63;
  const int wave = tid >> 6;
  const int wm = wave >> 2, wn = wave & 3;

  const int gy = gridDim.y;
  int f = blockIdx.x + gridDim.x * blockIdx.y;
  {
    const int nwg = gridDim.x * gy;
    const int q = nwg >> 3, rr = nwg & 7;
    const int xcd = f & 7, ix = f >> 3;
    f = (xcd < rr ? xcd * (q + 1) : rr * (q + 1) + (xcd - rr) * q) + ix;
  }
  const int bx = f / gy, by = f - gy * bx;
  const int m0 = by * 256, n0 = bx * 192;

  floatx4 acc[8][3];
#pragma unroll
  for (int i = 0; i < 8; i++)
#pragma unroll
    for (int j = 0; j < 3; j++) acc[i][j] = (floatx4){0.f, 0.f, 0.f, 0.f};

  const int rloc = tid >> 2, cch = tid & 3;
  const int gcol = ((cch ^ ((rloc >> 1) & 3)) * 8);
  const ushort_t* gA = A + (size_t)(m0 + rloc) * ldk + gcol;
  const ushort_t* gB = Bm + (size_t)(n0 + rloc) * ldk + gcol;
  const int lofs = rloc * 32 + cch * 8;

#define STGA32(bufi, kofs)                                              \
  {                                                                     \
    async16(gA + (kofs), &As[bufi][lofs]);                              \
    async16(gA + (size_t)128 * ldk + (kofs), &As[bufi][4096 + lofs]);   \
  }
// rows 0..127 then rows 64..191 (64..127 double-written, same bytes)
#define STGB32(bufi, kofs)                                              \
  {                                                                     \
    async16(gB + (kofs), &Bs[bufi][lofs]);                              \
    async16(gB + (size_t)64 * ldk + (kofs), &Bs[bufi][2048 + lofs]);    \
  }

  const int NT = Kd >> 5;  // K-tiles of 32
  STGA32(0, 0) STGB32(0, 0)
  if (NT > 1) { STGA32(1, 32) STGB32(1, 32) }
  if (NT > 2) { STGA32(2, 64) STGB32(2, 64) }
  if (NT > 2) asm volatile("s_waitcnt vmcnt(8)" ::: "memory");
  else if (NT > 1) asm volatile("s_waitcnt vmcnt(4)" ::: "memory");
  else asm volatile("s_waitcnt vmcnt(0)" ::: "memory");
  __builtin_amdgcn_s_barrier();

  const int fr = lane & 15, fq = lane >> 4;
  const int co = ((fq ^ ((fr >> 1) & 3)) * 8);
  const int aoff = (wm * 128 + fr) * 32 + co;
  const int boff = (wn * 48 + fr) * 32 + co;

  for (int kt = 0; kt < NT; ++kt) {
    const int cb = kt & 3;
    const int pb = (kt + 3) & 3;
    const int kof = (kt + 3) * 32;
    const bool sp = (kt + 3) < NT;
    const ushort_t* Ab = As[cb];
    const ushort_t* Bb = Bs[cb];
    short8 av[4], bv[3];

    // ---- phase 0 ----
#pragma unroll
    for (int i = 0; i < 4; i++) av[i] = *(const short8*)(Ab + aoff + i * 512);
#pragma unroll
    for (int j = 0; j < 3; j++) bv[j] = *(const short8*)(Bb + boff + j * 512);
    if (sp) STGA32(pb, kof)
    __builtin_amdgcn_s_barrier();
    asm volatile("s_waitcnt lgkmcnt(0)" ::: "memory");
    __builtin_amdgcn_s_setprio(1);
#pragma unroll
    for (int i = 0; i < 4; i++)
#pragma unroll
      for (int j = 0; j < 3; j++)
        acc[i][j] = __builtin_amdgcn_mfma_f32_16x16x32_bf16(av[i], bv[j], acc[i][j], 0, 0, 0);
    __builtin_amdgcn_s_setprio(0);
    __builtin_amdgcn_s_barrier();

    // ---- phase 1 ----
#pragma unroll
    for (int i = 0; i < 4; i++) av[i] = *(const short8*)(Ab + aoff + 2048 + i * 512);
    if (sp) STGB32(pb, kof)
    __builtin_amdgcn_s_barrier();
    asm volatile("s_waitcnt lgkmcnt(0)" ::: "memory");
    __builtin_amdgcn_s_setprio(1);
#pragma unroll
    for (int i = 0; i < 4; i++)
#pragma unroll
      for (int j = 0; j < 3; j++)
        acc[4 + i][j] = __builtin_amdgcn_mfma_f32_16x16x32_bf16(av[i], bv[j], acc[4 + i][j], 0, 0, 0);
    __builtin_amdgcn_s_setprio(0);
    if (kt + 3 < NT) asm volatile("s_waitcnt vmcnt(8)" ::: "memory");
    else if (kt + 2 < NT) asm volatile("s_waitcnt vmcnt(4)" ::: "memory");
    else asm volatile("s_waitcnt vmcnt(0)" ::: "memory");
    __builtin_amdgcn_s_barrier();
  }
#undef STGA32
#undef STGB32

  const int crow = m0 + wm * 128 + (lane >> 4) * 4;
  const int ccol = n0 + wn * 48 + (lane & 15);
#pragma unroll
  for (int mt = 0; mt < 8; mt++)
#pragma unroll
    for (int nt = 0; nt < 3; nt++) {
      floatx4 a = acc[mt][nt];
#pragma unroll
      for (int r = 0; r < 4; r++) {
        const int gm = crow + mt * 16 + r;
        const int gn = ccol + nt * 16;
        outB[(size_t)gm * N + gn] = f2b(a[r]);
      }
    }
}

// ---------------- split-K=2 reduction: out += P0 + P1 -----------------------
__launch_bounds__(256)
__global__ void reduce2(const float4* __restrict__ P, float4* __restrict__ out, int n4) {
  int i = blockIdx.x * blockDim.x + threadIdx.x;
  int st = gridDim.x * blockDim.x;
  for (; i < n4; i += st) {
    float4 a = out[i];
    float4 p0 = P[i], p1 = P[i + 1048576];
    a.x += p0.x + p1.x;
    a.y += p0.y + p1.y;
    a.z += p0.z + p1.z;
    a.w += p0.w + p1.w;
    out[i] = a;
  }
}

// ---------------- attention (degenerate mask -> diag + suffix sum) ----------
// z[q] = (e_q*v[q] + sum_{p>q} v[p]) / (e_q + (S-1-q)), e_q = exp(q.k/8)
__launch_bounds__(256)
__global__ void attn1(const ushort_t* __restrict__ qkv,
                      float* __restrict__ eG, float* __restrict__ psumG) {
  const int c = blockIdx.x & 63;
  const int i = (blockIdx.x >> 6) & 15;
  const int b = blockIdx.x >> 10;
  const int t = threadIdx.x;
  const int sg = t >> 3, h8 = (t & 7) * 8;
  const int s = c * 32 + sg;
  const size_t rb = (size_t)b * 2048 * 3072 + (size_t)s * 3072 + i * 64 + h8;
  short8 q8 = *(const short8*)(qkv + rb);
  short8 k8 = *(const short8*)(qkv + rb + 1024);
  short8 v8 = *(const short8*)(qkv + rb + 2048);
  float d = 0.f;
  float vf[8];
#pragma unroll
  for (int j = 0; j < 8; j++) {
    float qf = b2f((ushort_t)q8[j]);
    float kf = b2f((ushort_t)k8[j]);
    vf[j] = b2f((ushort_t)v8[j]);
    d += qf * kf;
  }
  d += __shfl_xor(d, 1, 64);
  d += __shfl_xor(d, 2, 64);
  d += __shfl_xor(d, 4, 64);
  if ((t & 7) == 0) eG[((size_t)(b * 16 + i)) * 2048 + s] = __expf(d * 0.125f);
  __shared__ float vs[32][68];  // +4 pad: b128 writes hit all 8 bank slots
#pragma unroll
  for (int j = 0; j < 8; j += 4)
    *(float4*)&vs[sg][h8 + j] = make_float4(vf[j], vf[j + 1], vf[j + 2], vf[j + 3]);
  __syncthreads();
  if (t < 64) {
    float acc = 0.f;
#pragma unroll 8
    for (int sgi = 0; sgi < 32; sgi++) acc += vs[sgi][t];
    psumG[(((size_t)(b * 16 + i)) * 64 + c) * 64 + t] = acc;
  }
}

// Pass 2 (R16): rcp hoisted off the serial chain; 4-acc suffix sum.
__launch_bounds__(256)
__global__ void attn2(const ushort_t* __restrict__ qkv,
                      const float* __restrict__ eG, const float* __restrict__ psumG,
                      ushort_t* __restrict__ Z) {
  const int wave = threadIdx.x >> 6, h = threadIdx.x & 63;
  const int c = (blockIdx.x & 15) * 4 + wave;
  const int i = (blockIdx.x >> 4) & 15;
  const int b = blockIdx.x >> 8;
  const size_t rowbase = (size_t)b * 2048 * 3072;
  const size_t pbase = ((size_t)(b * 16 + i)) * 64;
  float r0 = 0.f, r1 = 0.f, r2 = 0.f, r3 = 0.f;
  {
    int cc = c + 1;
    for (; cc + 3 < 64; cc += 4) {
      r0 += psumG[(pbase + cc) * 64 + h];
      r1 += psumG[(pbase + cc + 1) * 64 + h];
      r2 += psumG[(pbase + cc + 2) * 64 + h];
      r3 += psumG[(pbase + cc + 3) * 64 + h];
    }
    for (; cc < 64; cc++) r0 += psumG[(pbase + cc) * 64 + h];
  }
  float run = (r0 + r1) + (r2 + r3);
  const size_t ebase = ((size_t)(b * 16 + i)) * 2048;
  for (int t4 = 1; t4 >= 0; t4--) {
    float vv[16], num[16], rcp[16];
#pragma unroll
    for (int j = 0; j < 16; j++) {
      const int s = c * 32 + t4 * 16 + j;
      vv[j] = b2f(qkv[rowbase + (size_t)s * 3072 + 2048 + i * 64 + h]);
      float e = eG[ebase + s];
      num[j] = e * vv[j];
      float d = e + (float)(2047 - s);
      float r = __builtin_amdgcn_rcpf(d);
      rcp[j] = r * (2.f - d * r);  // one Newton step
    }
#pragma unroll
    for (int j = 15; j >= 0; j--) {
      const int s = c * 32 + t4 * 16 + j;
      float z = (num[j] + run) * rcp[j];
      Z[((size_t)b * 2048 + s) * 1024 + i * 64 + h] = f2b(z);
      run += vv[j];
    }
  }
}

// ---------------- launch ----------------------------------------------------
extern "C" void kernel_launch(void* const* d_in, const int* in_sizes, int n_in,
                              void* d_out, int out_size, void* d_ws, size_t ws_size,
                              hipStream_t stream) {
  const float* x     = (const float*)d_in[0];
  const float* W_Q   = (const float*)d_in[1];
  const float* W_K   = (const float*)d_in[2];
  const float* W_V   = (const float*)d_in[3];
  const float* W_O   = (const float*)d_in[4];
  const float* W_in  = (const float*)d_in[5];
  const float* b_in  = (const float*)d_in[6];
  const float* W_out = (const float*)d_in[7];
  const float* b_out = (const float*)d_in[8];
  float* out = (float*)d_out;

  // ws layout (max 104 MB).
  // P (32 MB) aliases [0,32): Xb/Wqkv/WOb/Z/QKV[0,8MB) all dead by MODE3
  // (stream-ordered). eG/psumG live inside Hb's region [72,104): consumed by
  // attn2 BEFORE MLP-in writes Hb, so no conflict.
  char* base = (char*)d_ws;
  const size_t MB = 1048576;
  ushort_t* Xb    = (ushort_t*)(base + 0 * MB);    // 8 MB
  ushort_t* Wqkv  = (ushort_t*)(base + 8 * MB);    // 6 MB
  ushort_t* WOb   = (ushort_t*)(base + 14 * MB);   // 2 MB
  ushort_t* Z     = (ushort_t*)(base + 16 * MB);   // 8 MB
  ushort_t* QKV   = (ushort_t*)(base + 24 * MB);   // 24 MB
  ushort_t* midb  = (ushort_t*)(base + 48 * MB);   // 8 MB
  ushort_t* Winb  = (ushort_t*)(base + 56 * MB);   // 8 MB
  ushort_t* Woutb = (ushort_t*)(base + 64 * MB);   // 8 MB
  ushort_t* Hb    = (ushort_t*)(base + 72 * MB);   // 32 MB
  float*    P     = (float*)(base + 0 * MB);       // 32 MB [0,32) alias
  float*    psumG = (float*)(base + 72 * MB);            // 512 KB (pre-MLP-in)
  float*    eG    = (float*)(base + 72 * MB + 524288);   // 256 KB (pre-MLP-in)

  Cvt7 ca;
  ca.src[0] = x;     ca.dst[0] = Xb;               ca.scale[0] = 1.f;
  ca.src[1] = W_Q;   ca.dst[1] = Wqkv;             ca.scale[1] = 1.f;
  ca.src[2] = W_K;   ca.dst[2] = Wqkv + 1048576;   ca.scale[2] = 1.f;
  ca.src[3] = W_V;   ca.dst[3] = Wqkv + 2097152;   ca.scale[3] = 1.f;
  ca.src[4] = W_O;   ca.dst[4] = WOb;              ca.scale[4] = 2.f;  // fold mid=2*attn_out
  ca.src[5] = W_in;  ca.dst[5] = Winb;             ca.scale[5] = 1.f;
  ca.src[6] = W_out; ca.dst[6] = Woutb;            ca.scale[6] = 1.f;
  unsigned n4s[7] = {1048576, 262144, 262144, 262144, 262144, 1048576, 1048576};
  unsigned acc4 = 0;
  for (int j = 0; j < 7; j++) { ca.start[j] = acc4; acc4 += n4s[j]; }
  ca.start[7] = acc4;
  cvt_all<<<dim3((acc4 + 255) / 256), dim3(256), 0, stream>>>(ca);

  // QKV = X * Wqkv^T [4096,3072]: 256x192 tile, grid 16x16 = 256 blocks
  // (full CU coverage; gemm256's 192 blocks left 64 CUs idle at the same
  // per-block tile time).
  gemm192<0><<<dim3(16, 16), 512, 0, stream>>>(Xb, Wqkv, 4096, 3072, 1024, 1024,
                                               QKV, nullptr, nullptr);
  // attention -> Z [4096, 1024] bf16
  attn1<<<dim3(2048), 256, 0, stream>>>(QKV, eG, psumG);
  attn2<<<dim3(512), 256, 0, stream>>>(QKV, eG, psumG, Z);
  // mid = Z*(2*W_O)^T: legacy path, y-coloc (full B = 2 MB fits L2).
  gemm_bt<1, 2, 1><<<dim3(8, 64), 256, 0, stream>>>(Z, WOb, 4096, 1024, 1024, 1024,
                                                    midb, out, b_out);
  // H = relu(mid*W_in^T + b_in) [4096,4096]: gemm256 R11 (best measured).
  gemm256<2><<<dim3(16, 16), 512, 0, stream>>>(midb, Winb, 4096, 4096, 1024, 1024,
                                               Hb, nullptr, b_in);
  // P[z] = H slice * W_out^T: split-K=2, MT=2 cluster2 (best measured).
  gemm_bt<3, 2, 2><<<dim3(8, 64, 2), 256, 0, stream>>>(Hb, Woutb, 4096, 1024, 2048, 4096,
                                                       nullptr, P, nullptr);
  // out += P0 + P1
  reduce2<<<dim3(1024), 256, 0, stream>>>((const float4*)P, (float4*)out, 1048576);
}

// Round 16
// 274.365 us; speedup vs baseline: 1.0314x; 1.0014x over previous
//
#include <hip/hip_runtime.h>
#include <hip/hip_bf16.h>
#include <stdint.h>

typedef unsigned short ushort_t;
typedef __attribute__((ext_vector_type(8))) short short8;
typedef __attribute__((ext_vector_type(4))) float floatx4;

#define DEV __device__ __forceinline__

DEV ushort_t f2b(float f) {
  uint32_t x = __float_as_uint(f);
  uint32_t r = (x + 0x7FFFu + ((x >> 16) & 1u)) >> 16;
  return (ushort_t)r;
}
DEV float b2f(ushort_t u) { return __uint_as_float(((uint32_t)u) << 16); }

DEV void async16(const ushort_t* g, ushort_t* l) {
  __builtin_amdgcn_global_load_lds(
      (const __attribute__((address_space(1))) void*)g,
      (__attribute__((address_space(3))) void*)l, 16, 0, 0);
}

// ---------------- fused fp32 -> bf16 conversion (one launch) ----------------
struct Cvt7 {
  const float* src[7];
  ushort_t* dst[7];
  float scale[7];
  unsigned start[8];  // prefix, in float4 units
};
__global__ void cvt_all(Cvt7 a) {
  unsigned idx = blockIdx.x * blockDim.x + threadIdx.x;
  if (idx >= a.start[7]) return;
  int seg = 0;
#pragma unroll
  for (int j = 1; j < 7; j++) seg += (idx >= a.start[j]) ? 1 : 0;
  unsigned off = idx - a.start[seg];
  float sc = a.scale[seg];
  float4 v = ((const float4*)a.src[seg])[off];
  ((ushort4*)a.dst[seg])[off] =
      make_ushort4(f2b(v.x * sc), f2b(v.y * sc), f2b(v.z * sc), f2b(v.w * sc));
}

// ---------------- legacy 128-wide bf16 GEMM ---------------------------------
// C[M,N] = A[M,K=ldk]*B[N,ldk]^T. Tile (32*MT)x128, 256 thr, BK=64, 2-barrier.
// MODE 1: outB = bf16(acc); outF = acc + bias   (mid; WOb pre-scaled x2)
// MODE 3: outF[z*M*N+idx] = acc                 (MLP-out split-K partials)
template <int MODE, int MT, int SWZ>
__launch_bounds__(256)
__global__ void gemm_bt(const ushort_t* __restrict__ A, const ushort_t* __restrict__ Bm,
                        int M, int N, int Kd, int ldk,
                        ushort_t* __restrict__ outB, float* __restrict__ outF,
                        const float* __restrict__ bias) {
  constexpr int TM = 32 * MT;
  __shared__ alignas(16) ushort_t As[TM * 64];
  __shared__ alignas(16) ushort_t Bs[128 * 64];
  const int tid = threadIdx.x;
  const int wave = tid >> 6, lane = tid & 63;
  const int wm = wave >> 1, wn = wave & 1;

  int bx, by;
  if constexpr (SWZ == 1) {
    const int f = blockIdx.x + gridDim.x * blockIdx.y;
    by = (f & 7) + 8 * (f / (8 * gridDim.x));
    bx = (f >> 3) % gridDim.x;
  } else if constexpr (SWZ == 2) {
    const int x = blockIdx.x, y = blockIdx.y;  // gx=8: XCD = x
    bx = 2 * (x & 3) + (y & 1);
    by = (y >> 1) + 32 * (x >> 2);
  } else {
    bx = blockIdx.x; by = blockIdx.y;
  }
  const int m0 = by * TM, n0 = bx * 128;
  const int kz = blockIdx.z * Kd;

  floatx4 acc[MT][4];
#pragma unroll
  for (int i = 0; i < MT; i++)
#pragma unroll
    for (int j = 0; j < 4; j++) acc[i][j] = (floatx4){0.f, 0.f, 0.f, 0.f};

  const int r8 = lane >> 3;
  const int scol = (((lane & 7) ^ (r8 & 7)) * 8);
  const ushort_t* gA = A + (size_t)(m0 + wave * (TM / 4) + r8) * ldk + kz + scol;
  const ushort_t* gB = Bm + (size_t)(n0 + wave * 32 + r8) * ldk + kz + scol;
  ushort_t* lA = As + wave * (TM / 4) * 64;
  ushort_t* lB = Bs + wave * 2048;

  const int fr = lane & 15, fq = lane >> 4;
  const int sw = fr & 7;
  const ushort_t* rdA = As + (wm * 16 * MT + fr) * 64;
  const ushort_t* rdB = Bs + (wn * 64 + fr) * 64;

  for (int k0 = 0; k0 < Kd; k0 += 64) {
#pragma unroll
    for (int j = 0; j < MT; j++) async16(gA + (size_t)j * 8 * ldk, lA + j * 512);
#pragma unroll
    for (int j = 0; j < 4; j++) async16(gB + (size_t)j * 8 * ldk, lB + j * 512);
    gA += 64; gB += 64;
    __syncthreads();
#pragma unroll
    for (int h = 0; h < 2; h++) {
      const int co = ((h * 4 + fq) ^ sw) * 8;
      short8 af[MT], bfv[4];
#pragma unroll
      for (int mt = 0; mt < MT; mt++) af[mt] = *(const short8*)(rdA + mt * 16 * 64 + co);
#pragma unroll
      for (int nt = 0; nt < 4; nt++) bfv[nt] = *(const short8*)(rdB + nt * 16 * 64 + co);
#pragma unroll
      for (int mt = 0; mt < MT; mt++)
#pragma unroll
        for (int nt = 0; nt < 4; nt++)
          acc[mt][nt] = __builtin_amdgcn_mfma_f32_16x16x32_bf16(af[mt], bfv[nt], acc[mt][nt], 0, 0, 0);
    }
    __syncthreads();
  }

  const int crow = m0 + wm * 16 * MT + (lane >> 4) * 4;
  const int ccol = n0 + wn * 64 + (lane & 15);
  const size_t zoff = (size_t)blockIdx.z * M * N;
#pragma unroll
  for (int mt = 0; mt < MT; mt++)
#pragma unroll
    for (int nt = 0; nt < 4; nt++) {
      floatx4 a = acc[mt][nt];
#pragma unroll
      for (int r = 0; r < 4; r++) {
        const int gm = crow + mt * 16 + r;
        const int gn = ccol + nt * 16;
        const size_t idx = (size_t)gm * N + gn;
        float v = a[r];
        if constexpr (MODE == 0) {
          outB[idx] = f2b(v);
        } else if constexpr (MODE == 1) {
          outB[idx] = f2b(v);          // WOb pre-scaled by 2 in cvt
          outF[idx] = v + bias[gn];
        } else if constexpr (MODE == 2) {
          float t = v + bias[gn];
          outB[idx] = f2b(t > 0.f ? t : 0.f);
        } else {
          outF[zoff + idx] = v;
        }
      }
    }
}

// ---------------- 256x256 pipelined bf16 GEMM (R11 schedule) ----------------
// Best measured for MLP-in (46-48us). 128KB LDS, 1 block/CU (exact coverage
// at grid 16x16 = 256 blocks; narrower tiles don't divide N=4096 or force
// two scheduling waves -> per-block-bound optimum for this structure).
// MODE 2: bf16(relu(acc+bias))
template <int MODE>
__launch_bounds__(512, 2)
__global__ void gemm256(const ushort_t* __restrict__ A, const ushort_t* __restrict__ Bm,
                        int M, int N, int Kd, int ldk,
                        ushort_t* __restrict__ outB, float* __restrict__ outF,
                        const float* __restrict__ bias) {
  __shared__ alignas(16) ushort_t As[4][256 * 32];
  __shared__ alignas(16) ushort_t Bs[4][256 * 32];
  const int tid = threadIdx.x;
  const int lane = tid & 63;
  const int wave = tid >> 6;
  const int wm = wave >> 2, wn = wave & 3;

  // bijective XCD-chunk swizzle on the flat (x,y) id (m204 form).
  const int gy = gridDim.y;
  int f = blockIdx.x + gridDim.x * blockIdx.y;
  {
    const int nwg = gridDim.x * gy;
    const int q = nwg >> 3, rr = nwg & 7;
    const int xcd = f & 7, ix = f >> 3;
    f = (xcd < rr ? xcd * (q + 1) : rr * (q + 1) + (xcd - rr) * q) + ix;
  }
  const int bx = f / gy, by = f - gy * bx;
  const int m0 = by * 256, n0 = bx * 256;
  const size_t kz = (size_t)blockIdx.z * Kd;

  floatx4 acc[8][4];
#pragma unroll
  for (int i = 0; i < 8; i++)
#pragma unroll
    for (int j = 0; j < 4; j++) acc[i][j] = (floatx4){0.f, 0.f, 0.f, 0.f};

  const int rloc = tid >> 2, cch = tid & 3;
  const int gcol = ((cch ^ ((rloc >> 1) & 3)) * 8);
  const ushort_t* gA = A + (size_t)(m0 + rloc) * ldk + kz + gcol;
  const ushort_t* gB = Bm + (size_t)(n0 + rloc) * ldk + kz + gcol;
  const int lofs = rloc * 32 + cch * 8;

#define STGA32(bufi, kofs)                                              \
  {                                                                     \
    async16(gA + (kofs), &As[bufi][lofs]);                              \
    async16(gA + (size_t)128 * ldk + (kofs), &As[bufi][4096 + lofs]);   \
  }
#define STGB32(bufi, kofs)                                              \
  {                                                                     \
    async16(gB + (kofs), &Bs[bufi][lofs]);                              \
    async16(gB + (size_t)128 * ldk + (kofs), &Bs[bufi][4096 + lofs]);   \
  }

  const int NT = Kd >> 5;  // K-tiles of 32
  STGA32(0, 0) STGB32(0, 0)
  if (NT > 1) { STGA32(1, 32) STGB32(1, 32) }
  if (NT > 2) { STGA32(2, 64) STGB32(2, 64) }
  if (NT > 2) asm volatile("s_waitcnt vmcnt(8)" ::: "memory");
  else if (NT > 1) asm volatile("s_waitcnt vmcnt(4)" ::: "memory");
  else asm volatile("s_waitcnt vmcnt(0)" ::: "memory");
  __builtin_amdgcn_s_barrier();

  const int fr = lane & 15, fq = lane >> 4;
  const int co = ((fq ^ ((fr >> 1) & 3)) * 8);
  const int aoff = (wm * 128 + fr) * 32 + co;
  const int boff = (wn * 64 + fr) * 32 + co;

  for (int kt = 0; kt < NT; ++kt) {
    const int cb = kt & 3;            // compute slot
    const int pb = (kt + 3) & 3;      // prefetch slot (== (kt-1)&3, freed)
    const int kof = (kt + 3) * 32;
    const bool sp = (kt + 3) < NT;
    const ushort_t* Ab = As[cb];
    const ushort_t* Bb = Bs[cb];
    short8 av[4], bv[4];

    // ---- phase 0: QM=0 (rows wm*128..+64), all 4 n-frags ----
#pragma unroll
    for (int i = 0; i < 4; i++) av[i] = *(const short8*)(Ab + aoff + i * 512);
#pragma unroll
    for (int j = 0; j < 4; j++) bv[j] = *(const short8*)(Bb + boff + j * 512);
    if (sp) STGA32(pb, kof)
    __builtin_amdgcn_s_barrier();
    asm volatile("s_waitcnt lgkmcnt(0)" ::: "memory");
    __builtin_amdgcn_s_setprio(1);
#pragma unroll
    for (int i = 0; i < 4; i++)
#pragma unroll
      for (int j = 0; j < 4; j++)
        acc[i][j] = __builtin_amdgcn_mfma_f32_16x16x32_bf16(av[i], bv[j], acc[i][j], 0, 0, 0);
    __builtin_amdgcn_s_setprio(0);
    __builtin_amdgcn_s_barrier();

    // ---- phase 1: QM=1 (rows wm*128+64..+64), reuse bv ----
#pragma unroll
    for (int i = 0; i < 4; i++) av[i] = *(const short8*)(Ab + aoff + 2048 + i * 512);
    if (sp) STGB32(pb, kof)
    __builtin_amdgcn_s_barrier();
    asm volatile("s_waitcnt lgkmcnt(0)" ::: "memory");
    __builtin_amdgcn_s_setprio(1);
#pragma unroll
    for (int i = 0; i < 4; i++)
#pragma unroll
      for (int j = 0; j < 4; j++)
        acc[4 + i][j] = __builtin_amdgcn_mfma_f32_16x16x32_bf16(av[i], bv[j], acc[4 + i][j], 0, 0, 0);
    __builtin_amdgcn_s_setprio(0);
    if (kt + 3 < NT) asm volatile("s_waitcnt vmcnt(8)" ::: "memory");
    else if (kt + 2 < NT) asm volatile("s_waitcnt vmcnt(4)" ::: "memory");
    else asm volatile("s_waitcnt vmcnt(0)" ::: "memory");
    __builtin_amdgcn_s_barrier();
  }
#undef STGA32
#undef STGB32

  const int crow = m0 + wm * 128 + (lane >> 4) * 4;
  const int ccol = n0 + wn * 64 + (lane & 15);
#pragma unroll
  for (int mt = 0; mt < 8; mt++)
#pragma unroll
    for (int nt = 0; nt < 4; nt++) {
      floatx4 a = acc[mt][nt];
#pragma unroll
      for (int r = 0; r < 4; r++) {
        const int gm = crow + mt * 16 + r;
        const int gn = ccol + nt * 16;
        const size_t idx = (size_t)gm * N + gn;
        if constexpr (MODE == 0) {
          outB[idx] = f2b(a[r]);
        } else if constexpr (MODE == 2) {
          float t = a[r] + bias[gn];
          outB[idx] = f2b(t > 0.f ? t : 0.f);
        } else {
          outF[idx] = a[r];
        }
      }
    }
}

// ---------------- 256x192 pipelined bf16 GEMM (R24, QKV) --------------------
// Same R11 schedule/sync as gemm256; tile narrowed to 256x192 so the QKV
// grid becomes 16x16 = 256 blocks (full CU coverage; 256x256 gave 192
// blocks with 64 CUs idle -> kernel was per-block-bound). Verified R15:
// total -4.4us. B's 192 rows staged as two 128-row calls at row offsets
// 0 and 64 (rows 64..127 double-written, same bytes, benign). K-order per
// acc unchanged -> bitwise-same QKV. LDS 112 KB.
template <int MODE>
__launch_bounds__(512, 2)
__global__ void gemm192(const ushort_t* __restrict__ A, const ushort_t* __restrict__ Bm,
                        int M, int N, int Kd, int ldk,
                        ushort_t* __restrict__ outB, float* __restrict__ outF,
                        const float* __restrict__ bias) {
  __shared__ alignas(16) ushort_t As[4][256 * 32];
  __shared__ alignas(16) ushort_t Bs[4][192 * 32];
  const int tid = threadIdx.x;
  const int lane = tid & 63;
  const int wave = tid >> 6;
  const int wm = wave >> 2, wn = wave & 3;

  const int gy = gridDim.y;
  int f = blockIdx.x + gridDim.x * blockIdx.y;
  {
    const int nwg = gridDim.x * gy;
    const int q = nwg >> 3, rr = nwg & 7;
    const int xcd = f & 7, ix = f >> 3;
    f = (xcd < rr ? xcd * (q + 1) : rr * (q + 1) + (xcd - rr) * q) + ix;
  }
  const int bx = f / gy, by = f - gy * bx;
  const int m0 = by * 256, n0 = bx * 192;

  floatx4 acc[8][3];
#pragma unroll
  for (int i = 0; i < 8; i++)
#pragma unroll
    for (int j = 0; j < 3; j++) acc[i][j] = (floatx4){0.f, 0.f, 0.f, 0.f};

  const int rloc = tid >> 2, cch = tid & 3;
  const int gcol = ((cch ^ ((rloc >> 1) & 3)) * 8);
  const ushort_t* gA = A + (size_t)(m0 + rloc) * ldk + gcol;
  const ushort_t* gB = Bm + (size_t)(n0 + rloc) * ldk + gcol;
  const int lofs = rloc * 32 + cch * 8;

#define STGA32(bufi, kofs)                                              \
  {                                                                     \
    async16(gA + (kofs), &As[bufi][lofs]);                              \
    async16(gA + (size_t)128 * ldk + (kofs), &As[bufi][4096 + lofs]);   \
  }
// rows 0..127 then rows 64..191 (64..127 double-written, same bytes)
#define STGB32(bufi, kofs)                                              \
  {                                                                     \
    async16(gB + (kofs), &Bs[bufi][lofs]);                              \
    async16(gB + (size_t)64 * ldk + (kofs), &Bs[bufi][2048 + lofs]);    \
  }

  const int NT = Kd >> 5;  // K-tiles of 32
  STGA32(0, 0) STGB32(0, 0)
  if (NT > 1) { STGA32(1, 32) STGB32(1, 32) }
  if (NT > 2) { STGA32(2, 64) STGB32(2, 64) }
  if (NT > 2) asm volatile("s_waitcnt vmcnt(8)" ::: "memory");
  else if (NT > 1) asm volatile("s_waitcnt vmcnt(4)" ::: "memory");
  else asm volatile("s_waitcnt vmcnt(0)" ::: "memory");
  __builtin_amdgcn_s_barrier();

  const int fr = lane & 15, fq = lane >> 4;
  const int co = ((fq ^ ((fr >> 1) & 3)) * 8);
  const int aoff = (wm * 128 + fr) * 32 + co;
  const int boff = (wn * 48 + fr) * 32 + co;

  for (int kt = 0; kt < NT; ++kt) {
    const int cb = kt & 3;
    const int pb = (kt + 3) & 3;
    const int kof = (kt + 3) * 32;
    const bool sp = (kt + 3) < NT;
    const ushort_t* Ab = As[cb];
    const ushort_t* Bb = Bs[cb];
    short8 av[4], bv[3];

    // ---- phase 0 ----
#pragma unroll
    for (int i = 0; i < 4; i++) av[i] = *(const short8*)(Ab + aoff + i * 512);
#pragma unroll
    for (int j = 0; j < 3; j++) bv[j] = *(const short8*)(Bb + boff + j * 512);
    if (sp) STGA32(pb, kof)
    __builtin_amdgcn_s_barrier();
    asm volatile("s_waitcnt lgkmcnt(0)" ::: "memory");
    __builtin_amdgcn_s_setprio(1);
#pragma unroll
    for (int i = 0; i < 4; i++)
#pragma unroll
      for (int j = 0; j < 3; j++)
        acc[i][j] = __builtin_amdgcn_mfma_f32_16x16x32_bf16(av[i], bv[j], acc[i][j], 0, 0, 0);
    __builtin_amdgcn_s_setprio(0);
    __builtin_amdgcn_s_barrier();

    // ---- phase 1 ----
#pragma unroll
    for (int i = 0; i < 4; i++) av[i] = *(const short8*)(Ab + aoff + 2048 + i * 512);
    if (sp) STGB32(pb, kof)
    __builtin_amdgcn_s_barrier();
    asm volatile("s_waitcnt lgkmcnt(0)" ::: "memory");
    __builtin_amdgcn_s_setprio(1);
#pragma unroll
    for (int i = 0; i < 4; i++)
#pragma unroll
      for (int j = 0; j < 3; j++)
        acc[4 + i][j] = __builtin_amdgcn_mfma_f32_16x16x32_bf16(av[i], bv[j], acc[4 + i][j], 0, 0, 0);
    __builtin_amdgcn_s_setprio(0);
    if (kt + 3 < NT) asm volatile("s_waitcnt vmcnt(8)" ::: "memory");
    else if (kt + 2 < NT) asm volatile("s_waitcnt vmcnt(4)" ::: "memory");
    else asm volatile("s_waitcnt vmcnt(0)" ::: "memory");
    __builtin_amdgcn_s_barrier();
  }
#undef STGA32
#undef STGB32

  const int crow = m0 + wm * 128 + (lane >> 4) * 4;
  const int ccol = n0 + wn * 48 + (lane & 15);
#pragma unroll
  for (int mt = 0; mt < 8; mt++)
#pragma unroll
    for (int nt = 0; nt < 3; nt++) {
      floatx4 a = acc[mt][nt];
#pragma unroll
      for (int r = 0; r < 4; r++) {
        const int gm = crow + mt * 16 + r;
        const int gn = ccol + nt * 16;
        outB[(size_t)gm * N + gn] = f2b(a[r]);
      }
    }
}

// ---------------- split-K=2 reduction: out += P0 + P1 -----------------------
__launch_bounds__(256)
__global__ void reduce2(const float4* __restrict__ P, float4* __restrict__ out, int n4) {
  int i = blockIdx.x * blockDim.x + threadIdx.x;
  int st = gridDim.x * blockDim.x;
  for (; i < n4; i += st) {
    float4 a = out[i];
    float4 p0 = P[i], p1 = P[i + 1048576];
    a.x += p0.x + p1.x;
    a.y += p0.y + p1.y;
    a.z += p0.z + p1.z;
    a.w += p0.w + p1.w;
    out[i] = a;
  }
}

// ---------------- attention (degenerate mask -> diag + suffix sum) ----------
// z[q] = (e_q*v[q] + sum_{p>q} v[p]) / (e_q + (S-1-q)), e_q = exp(q.k/8)
__launch_bounds__(256)
__global__ void attn1(const ushort_t* __restrict__ qkv,
                      float* __restrict__ eG, float* __restrict__ psumG) {
  const int c = blockIdx.x & 63;
  const int i = (blockIdx.x >> 6) & 15;
  const int b = blockIdx.x >> 10;
  const int t = threadIdx.x;
  const int sg = t >> 3, h8 = (t & 7) * 8;
  const int s = c * 32 + sg;
  const size_t rb = (size_t)b * 2048 * 3072 + (size_t)s * 3072 + i * 64 + h8;
  short8 q8 = *(const short8*)(qkv + rb);
  short8 k8 = *(const short8*)(qkv + rb + 1024);
  short8 v8 = *(const short8*)(qkv + rb + 2048);
  float d = 0.f;
  float vf[8];
#pragma unroll
  for (int j = 0; j < 8; j++) {
    float qf = b2f((ushort_t)q8[j]);
    float kf = b2f((ushort_t)k8[j]);
    vf[j] = b2f((ushort_t)v8[j]);
    d += qf * kf;
  }
  d += __shfl_xor(d, 1, 64);
  d += __shfl_xor(d, 2, 64);
  d += __shfl_xor(d, 4, 64);
  if ((t & 7) == 0) eG[((size_t)(b * 16 + i)) * 2048 + s] = __expf(d * 0.125f);
  __shared__ float vs[32][68];  // +4 pad: b128 writes hit all 8 bank slots
#pragma unroll
  for (int j = 0; j < 8; j += 4)
    *(float4*)&vs[sg][h8 + j] = make_float4(vf[j], vf[j + 1], vf[j + 2], vf[j + 3]);
  __syncthreads();
  if (t < 64) {
    float acc = 0.f;
#pragma unroll 8
    for (int sgi = 0; sgi < 32; sgi++) acc += vs[sgi][t];
    psumG[(((size_t)(b * 16 + i)) * 64 + c) * 64 + t] = acc;
  }
}

// Pass 2 (R16): rcp hoisted off the serial chain; 4-acc suffix sum.
__launch_bounds__(256)
__global__ void attn2(const ushort_t* __restrict__ qkv,
                      const float* __restrict__ eG, const float* __restrict__ psumG,
                      ushort_t* __restrict__ Z) {
  const int wave = threadIdx.x >> 6, h = threadIdx.x & 63;
  const int c = (blockIdx.x & 15) * 4 + wave;
  const int i = (blockIdx.x >> 4) & 15;
  const int b = blockIdx.x >> 8;
  const size_t rowbase = (size_t)b * 2048 * 3072;
  const size_t pbase = ((size_t)(b * 16 + i)) * 64;
  float r0 = 0.f, r1 = 0.f, r2 = 0.f, r3 = 0.f;
  {
    int cc = c + 1;
    for (; cc + 3 < 64; cc += 4) {
      r0 += psumG[(pbase + cc) * 64 + h];
      r1 += psumG[(pbase + cc + 1) * 64 + h];
      r2 += psumG[(pbase + cc + 2) * 64 + h];
      r3 += psumG[(pbase + cc + 3) * 64 + h];
    }
    for (; cc < 64; cc++) r0 += psumG[(pbase + cc) * 64 + h];
  }
  float run = (r0 + r1) + (r2 + r3);
  const size_t ebase = ((size_t)(b * 16 + i)) * 2048;
  for (int t4 = 1; t4 >= 0; t4--) {
    float vv[16], num[16], rcp[16];
#pragma unroll
    for (int j = 0; j < 16; j++) {
      const int s = c * 32 + t4 * 16 + j;
      vv[j] = b2f(qkv[rowbase + (size_t)s * 3072 + 2048 + i * 64 + h]);
      float e = eG[ebase + s];
      num[j] = e * vv[j];
      float d = e + (float)(2047 - s);
      float r = __builtin_amdgcn_rcpf(d);
      rcp[j] = r * (2.f - d * r);  // one Newton step
    }
#pragma unroll
    for (int j = 15; j >= 0; j--) {
      const int s = c * 32 + t4 * 16 + j;
      float z = (num[j] + run) * rcp[j];
      Z[((size_t)b * 2048 + s) * 1024 + i * 64 + h] = f2b(z);
      run += vv[j];
    }
  }
}

// ---------------- launch ----------------------------------------------------
extern "C" void kernel_launch(void* const* d_in, const int* in_sizes, int n_in,
                              void* d_out, int out_size, void* d_ws, size_t ws_size,
                              hipStream_t stream) {
  const float* x     = (const float*)d_in[0];
  const float* W_Q   = (const float*)d_in[1];
  const float* W_K   = (const float*)d_in[2];
  const float* W_V   = (const float*)d_in[3];
  const float* W_O   = (const float*)d_in[4];
  const float* W_in  = (const float*)d_in[5];
  const float* b_in  = (const float*)d_in[6];
  const float* W_out = (const float*)d_in[7];
  const float* b_out = (const float*)d_in[8];
  float* out = (float*)d_out;

  // ws layout (max 104 MB).
  // P (32 MB) aliases [0,32): Xb/Wqkv/WOb/Z/QKV[0,8MB) all dead by MODE3
  // (stream-ordered). eG/psumG live inside Hb's region [72,104): consumed by
  // attn2 BEFORE MLP-in writes Hb, so no conflict.
  char* base = (char*)d_ws;
  const size_t MB = 1048576;
  ushort_t* Xb    = (ushort_t*)(base + 0 * MB);    // 8 MB
  ushort_t* Wqkv  = (ushort_t*)(base + 8 * MB);    // 6 MB
  ushort_t* WOb   = (ushort_t*)(base + 14 * MB);   // 2 MB
  ushort_t* Z     = (ushort_t*)(base + 16 * MB);   // 8 MB
  ushort_t* QKV   = (ushort_t*)(base + 24 * MB);   // 24 MB
  ushort_t* midb  = (ushort_t*)(base + 48 * MB);   // 8 MB
  ushort_t* Winb  = (ushort_t*)(base + 56 * MB);   // 8 MB
  ushort_t* Woutb = (ushort_t*)(base + 64 * MB);   // 8 MB
  ushort_t* Hb    = (ushort_t*)(base + 72 * MB);   // 32 MB
  float*    P     = (float*)(base + 0 * MB);       // 32 MB [0,32) alias
  float*    psumG = (float*)(base + 72 * MB);            // 512 KB (pre-MLP-in)
  float*    eG    = (float*)(base + 72 * MB + 524288);   // 256 KB (pre-MLP-in)

  Cvt7 ca;
  ca.src[0] = x;     ca.dst[0] = Xb;               ca.scale[0] = 1.f;
  ca.src[1] = W_Q;   ca.dst[1] = Wqkv;             ca.scale[1] = 1.f;
  ca.src[2] = W_K;   ca.dst[2] = Wqkv + 1048576;   ca.scale[2] = 1.f;
  ca.src[3] = W_V;   ca.dst[3] = Wqkv + 2097152;   ca.scale[3] = 1.f;
  ca.src[4] = W_O;   ca.dst[4] = WOb;              ca.scale[4] = 2.f;  // fold mid=2*attn_out
  ca.src[5] = W_in;  ca.dst[5] = Winb;             ca.scale[5] = 1.f;
  ca.src[6] = W_out; ca.dst[6] = Woutb;            ca.scale[6] = 1.f;
  unsigned n4s[7] = {1048576, 262144, 262144, 262144, 262144, 1048576, 1048576};
  unsigned acc4 = 0;
  for (int j = 0; j < 7; j++) { ca.start[j] = acc4; acc4 += n4s[j]; }
  ca.start[7] = acc4;
  cvt_all<<<dim3((acc4 + 255) / 256), dim3(256), 0, stream>>>(ca);

  // QKV = X * Wqkv^T [4096,3072]: 256x192 tile, grid 16x16 = 256 blocks
  // (full CU coverage; R15 verified -4.4us vs 256x256's 192 blocks).
  gemm192<0><<<dim3(16, 16), 512, 0, stream>>>(Xb, Wqkv, 4096, 3072, 1024, 1024,
                                               QKV, nullptr, nullptr);
  // attention -> Z [4096, 1024] bf16
  attn1<<<dim3(2048), 256, 0, stream>>>(QKV, eG, psumG);
  attn2<<<dim3(512), 256, 0, stream>>>(QKV, eG, psumG, Z);
  // mid = Z*(2*W_O)^T: legacy path, y-coloc (full B = 2 MB fits L2).
  gemm_bt<1, 2, 1><<<dim3(8, 64), 256, 0, stream>>>(Z, WOb, 4096, 1024, 1024, 1024,
                                                    midb, out, b_out);
  // H = relu(mid*W_in^T + b_in) [4096,4096]: gemm256 R11 (best measured).
  gemm256<2><<<dim3(16, 16), 512, 0, stream>>>(midb, Winb, 4096, 4096, 1024, 1024,
                                               Hb, nullptr, b_in);
  // P[z] = H slice * W_out^T: split-K=2, MT=2 cluster2 (best measured).
  gemm_bt<3, 2, 2><<<dim3(8, 64, 2), 256, 0, stream>>>(Hb, Woutb, 4096, 1024, 2048, 4096,
                                                       nullptr, P, nullptr);
  // out += P0 + P1
  reduce2<<<dim3(1024), 256, 0, stream>>>((const float4*)P, (float4*)out, 1048576);
}

// Round 17
// 273.720 us; speedup vs baseline: 1.0339x; 1.0024x over previous
//
#include <hip/hip_runtime.h>
#include <hip/hip_bf16.h>
#include <stdint.h>

typedef unsigned short ushort_t;
typedef __attribute__((ext_vector_type(8))) short short8;
typedef __attribute__((ext_vector_type(4))) float floatx4;

#define DEV __device__ __forceinline__

DEV ushort_t f2b(float f) {
  uint32_t x = __float_as_uint(f);
  uint32_t r = (x + 0x7FFFu + ((x >> 16) & 1u)) >> 16;
  return (ushort_t)r;
}
DEV float b2f(ushort_t u) { return __uint_as_float(((uint32_t)u) << 16); }

DEV void async16(const ushort_t* g, ushort_t* l) {
  __builtin_amdgcn_global_load_lds(
      (const __attribute__((address_space(1))) void*)g,
      (__attribute__((address_space(3))) void*)l, 16, 0, 0);
}

// ---------------- fused fp32 -> bf16 conversion (one launch) ----------------
struct Cvt7 {
  const float* src[7];
  ushort_t* dst[7];
  float scale[7];
  unsigned start[8];  // prefix, in float4 units
};
__global__ void cvt_all(Cvt7 a) {
  unsigned idx = blockIdx.x * blockDim.x + threadIdx.x;
  if (idx >= a.start[7]) return;
  int seg = 0;
#pragma unroll
  for (int j = 1; j < 7; j++) seg += (idx >= a.start[j]) ? 1 : 0;
  unsigned off = idx - a.start[seg];
  float sc = a.scale[seg];
  float4 v = ((const float4*)a.src[seg])[off];
  ((ushort4*)a.dst[seg])[off] =
      make_ushort4(f2b(v.x * sc), f2b(v.y * sc), f2b(v.z * sc), f2b(v.w * sc));
}

// ---------------- legacy 128-wide bf16 GEMM ---------------------------------
// C[M,N] = A[M,K=ldk]*B[N,ldk]^T. Tile (32*MT)x128, 256 thr, BK=64, 2-barrier.
// MODE 1: outB = bf16(acc); outF = acc + bias   (mid; WOb pre-scaled x2)
// MODE 3: outF[z*M*N+idx] = acc                 (MLP-out split-K partials)
// SWZ=2: 2bx x 32by cluster/XCD (A 8MB/XCD -> ~2x HBM refetch, R10-measured)
// SWZ=3 (R25): 4bx x 16by cluster/XCD -> A 4MB (L2-sized) + B 2MB. Tests the
// per-XCD footprint model's prediction that FETCH drops 73.8 -> ~60 MB.
template <int MODE, int MT, int SWZ>
__launch_bounds__(256)
__global__ void gemm_bt(const ushort_t* __restrict__ A, const ushort_t* __restrict__ Bm,
                        int M, int N, int Kd, int ldk,
                        ushort_t* __restrict__ outB, float* __restrict__ outF,
                        const float* __restrict__ bias) {
  constexpr int TM = 32 * MT;
  __shared__ alignas(16) ushort_t As[TM * 64];
  __shared__ alignas(16) ushort_t Bs[128 * 64];
  const int tid = threadIdx.x;
  const int wave = tid >> 6, lane = tid & 63;
  const int wm = wave >> 1, wn = wave & 1;

  int bx, by;
  if constexpr (SWZ == 1) {
    const int f = blockIdx.x + gridDim.x * blockIdx.y;
    by = (f & 7) + 8 * (f / (8 * gridDim.x));
    bx = (f >> 3) % gridDim.x;
  } else if constexpr (SWZ == 2) {
    const int x = blockIdx.x, y = blockIdx.y;  // gx=8: XCD = x
    bx = 2 * (x & 3) + (y & 1);
    by = (y >> 1) + 32 * (x >> 2);
  } else if constexpr (SWZ == 3) {
    const int x = blockIdx.x, y = blockIdx.y;  // gx=8: XCD = x (z stride 512)
    bx = ((x >> 2) << 2) + (y & 3);            // 2 bx-groups of 4
    by = ((x & 3) << 4) + (y >> 2);            // 4 by-groups of 16
  } else {
    bx = blockIdx.x; by = blockIdx.y;
  }
  const int m0 = by * TM, n0 = bx * 128;
  const int kz = blockIdx.z * Kd;

  floatx4 acc[MT][4];
#pragma unroll
  for (int i = 0; i < MT; i++)
#pragma unroll
    for (int j = 0; j < 4; j++) acc[i][j] = (floatx4){0.f, 0.f, 0.f, 0.f};

  const int r8 = lane >> 3;
  const int scol = (((lane & 7) ^ (r8 & 7)) * 8);
  const ushort_t* gA = A + (size_t)(m0 + wave * (TM / 4) + r8) * ldk + kz + scol;
  const ushort_t* gB = Bm + (size_t)(n0 + wave * 32 + r8) * ldk + kz + scol;
  ushort_t* lA = As + wave * (TM / 4) * 64;
  ushort_t* lB = Bs + wave * 2048;

  const int fr = lane & 15, fq = lane >> 4;
  const int sw = fr & 7;
  const ushort_t* rdA = As + (wm * 16 * MT + fr) * 64;
  const ushort_t* rdB = Bs + (wn * 64 + fr) * 64;

  for (int k0 = 0; k0 < Kd; k0 += 64) {
#pragma unroll
    for (int j = 0; j < MT; j++) async16(gA + (size_t)j * 8 * ldk, lA + j * 512);
#pragma unroll
    for (int j = 0; j < 4; j++) async16(gB + (size_t)j * 8 * ldk, lB + j * 512);
    gA += 64; gB += 64;
    __syncthreads();
#pragma unroll
    for (int h = 0; h < 2; h++) {
      const int co = ((h * 4 + fq) ^ sw) * 8;
      short8 af[MT], bfv[4];
#pragma unroll
      for (int mt = 0; mt < MT; mt++) af[mt] = *(const short8*)(rdA + mt * 16 * 64 + co);
#pragma unroll
      for (int nt = 0; nt < 4; nt++) bfv[nt] = *(const short8*)(rdB + nt * 16 * 64 + co);
#pragma unroll
      for (int mt = 0; mt < MT; mt++)
#pragma unroll
        for (int nt = 0; nt < 4; nt++)
          acc[mt][nt] = __builtin_amdgcn_mfma_f32_16x16x32_bf16(af[mt], bfv[nt], acc[mt][nt], 0, 0, 0);
    }
    __syncthreads();
  }

  const int crow = m0 + wm * 16 * MT + (lane >> 4) * 4;
  const int ccol = n0 + wn * 64 + (lane & 15);
  const size_t zoff = (size_t)blockIdx.z * M * N;
#pragma unroll
  for (int mt = 0; mt < MT; mt++)
#pragma unroll
    for (int nt = 0; nt < 4; nt++) {
      floatx4 a = acc[mt][nt];
#pragma unroll
      for (int r = 0; r < 4; r++) {
        const int gm = crow + mt * 16 + r;
        const int gn = ccol + nt * 16;
        const size_t idx = (size_t)gm * N + gn;
        float v = a[r];
        if constexpr (MODE == 0) {
          outB[idx] = f2b(v);
        } else if constexpr (MODE == 1) {
          outB[idx] = f2b(v);          // WOb pre-scaled by 2 in cvt
          outF[idx] = v + bias[gn];
        } else if constexpr (MODE == 2) {
          float t = v + bias[gn];
          outB[idx] = f2b(t > 0.f ? t : 0.f);
        } else {
          outF[zoff + idx] = v;
        }
      }
    }
}

// ---------------- 256x256 pipelined bf16 GEMM (R11 schedule) ----------------
// Best measured for MLP-in (46-48us). 128KB LDS, 1 block/CU (exact coverage
// at grid 16x16 = 256 blocks).
// MODE 2: bf16(relu(acc+bias))
template <int MODE>
__launch_bounds__(512, 2)
__global__ void gemm256(const ushort_t* __restrict__ A, const ushort_t* __restrict__ Bm,
                        int M, int N, int Kd, int ldk,
                        ushort_t* __restrict__ outB, float* __restrict__ outF,
                        const float* __restrict__ bias) {
  __shared__ alignas(16) ushort_t As[4][256 * 32];
  __shared__ alignas(16) ushort_t Bs[4][256 * 32];
  const int tid = threadIdx.x;
  const int lane = tid & 63;
  const int wave = tid >> 6;
  const int wm = wave >> 2, wn = wave & 3;

  // bijective XCD-chunk swizzle on the flat (x,y) id (m204 form).
  const int gy = gridDim.y;
  int f = blockIdx.x + gridDim.x * blockIdx.y;
  {
    const int nwg = gridDim.x * gy;
    const int q = nwg >> 3, rr = nwg & 7;
    const int xcd = f & 7, ix = f >> 3;
    f = (xcd < rr ? xcd * (q + 1) : rr * (q + 1) + (xcd - rr) * q) + ix;
  }
  const int bx = f / gy, by = f - gy * bx;
  const int m0 = by * 256, n0 = bx * 256;
  const size_t kz = (size_t)blockIdx.z * Kd;

  floatx4 acc[8][4];
#pragma unroll
  for (int i = 0; i < 8; i++)
#pragma unroll
    for (int j = 0; j < 4; j++) acc[i][j] = (floatx4){0.f, 0.f, 0.f, 0.f};

  const int rloc = tid >> 2, cch = tid & 3;
  const int gcol = ((cch ^ ((rloc >> 1) & 3)) * 8);
  const ushort_t* gA = A + (size_t)(m0 + rloc) * ldk + kz + gcol;
  const ushort_t* gB = Bm + (size_t)(n0 + rloc) * ldk + kz + gcol;
  const int lofs = rloc * 32 + cch * 8;

#define STGA32(bufi, kofs)                                              \
  {                                                                     \
    async16(gA + (kofs), &As[bufi][lofs]);                              \
    async16(gA + (size_t)128 * ldk + (kofs), &As[bufi][4096 + lofs]);   \
  }
#define STGB32(bufi, kofs)                                              \
  {                                                                     \
    async16(gB + (kofs), &Bs[bufi][lofs]);                              \
    async16(gB + (size_t)128 * ldk + (kofs), &Bs[bufi][4096 + lofs]);   \
  }

  const int NT = Kd >> 5;  // K-tiles of 32
  STGA32(0, 0) STGB32(0, 0)
  if (NT > 1) { STGA32(1, 32) STGB32(1, 32) }
  if (NT > 2) { STGA32(2, 64) STGB32(2, 64) }
  if (NT > 2) asm volatile("s_waitcnt vmcnt(8)" ::: "memory");
  else if (NT > 1) asm volatile("s_waitcnt vmcnt(4)" ::: "memory");
  else asm volatile("s_waitcnt vmcnt(0)" ::: "memory");
  __builtin_amdgcn_s_barrier();

  const int fr = lane & 15, fq = lane >> 4;
  const int co = ((fq ^ ((fr >> 1) & 3)) * 8);
  const int aoff = (wm * 128 + fr) * 32 + co;
  const int boff = (wn * 64 + fr) * 32 + co;

  for (int kt = 0; kt < NT; ++kt) {
    const int cb = kt & 3;            // compute slot
    const int pb = (kt + 3) & 3;      // prefetch slot (== (kt-1)&3, freed)
    const int kof = (kt + 3) * 32;
    const bool sp = (kt + 3) < NT;
    const ushort_t* Ab = As[cb];
    const ushort_t* Bb = Bs[cb];
    short8 av[4], bv[4];

    // ---- phase 0: QM=0 (rows wm*128..+64), all 4 n-frags ----
#pragma unroll
    for (int i = 0; i < 4; i++) av[i] = *(const short8*)(Ab + aoff + i * 512);
#pragma unroll
    for (int j = 0; j < 4; j++) bv[j] = *(const short8*)(Bb + boff + j * 512);
    if (sp) STGA32(pb, kof)
    __builtin_amdgcn_s_barrier();
    asm volatile("s_waitcnt lgkmcnt(0)" ::: "memory");
    __builtin_amdgcn_s_setprio(1);
#pragma unroll
    for (int i = 0; i < 4; i++)
#pragma unroll
      for (int j = 0; j < 4; j++)
        acc[i][j] = __builtin_amdgcn_mfma_f32_16x16x32_bf16(av[i], bv[j], acc[i][j], 0, 0, 0);
    __builtin_amdgcn_s_setprio(0);
    __builtin_amdgcn_s_barrier();

    // ---- phase 1: QM=1 (rows wm*128+64..+64), reuse bv ----
#pragma unroll
    for (int i = 0; i < 4; i++) av[i] = *(const short8*)(Ab + aoff + 2048 + i * 512);
    if (sp) STGB32(pb, kof)
    __builtin_amdgcn_s_barrier();
    asm volatile("s_waitcnt lgkmcnt(0)" ::: "memory");
    __builtin_amdgcn_s_setprio(1);
#pragma unroll
    for (int i = 0; i < 4; i++)
#pragma unroll
      for (int j = 0; j < 4; j++)
        acc[4 + i][j] = __builtin_amdgcn_mfma_f32_16x16x32_bf16(av[i], bv[j], acc[4 + i][j], 0, 0, 0);
    __builtin_amdgcn_s_setprio(0);
    if (kt + 3 < NT) asm volatile("s_waitcnt vmcnt(8)" ::: "memory");
    else if (kt + 2 < NT) asm volatile("s_waitcnt vmcnt(4)" ::: "memory");
    else asm volatile("s_waitcnt vmcnt(0)" ::: "memory");
    __builtin_amdgcn_s_barrier();
  }
#undef STGA32
#undef STGB32

  const int crow = m0 + wm * 128 + (lane >> 4) * 4;
  const int ccol = n0 + wn * 64 + (lane & 15);
#pragma unroll
  for (int mt = 0; mt < 8; mt++)
#pragma unroll
    for (int nt = 0; nt < 4; nt++) {
      floatx4 a = acc[mt][nt];
#pragma unroll
      for (int r = 0; r < 4; r++) {
        const int gm = crow + mt * 16 + r;
        const int gn = ccol + nt * 16;
        const size_t idx = (size_t)gm * N + gn;
        if constexpr (MODE == 0) {
          outB[idx] = f2b(a[r]);
        } else if constexpr (MODE == 2) {
          float t = a[r] + bias[gn];
          outB[idx] = f2b(t > 0.f ? t : 0.f);
        } else {
          outF[idx] = a[r];
        }
      }
    }
}

// ---------------- 256x192 pipelined bf16 GEMM (QKV) -------------------------
// Same R11 schedule/sync as gemm256; tile narrowed to 256x192 so the QKV
// grid becomes 16x16 = 256 blocks (full CU coverage). R15 verified -4.4us.
// B's 192 rows staged as two 128-row calls at row offsets 0 and 64 (rows
// 64..127 double-written, same bytes, benign). LDS 112 KB.
template <int MODE>
__launch_bounds__(512, 2)
__global__ void gemm192(const ushort_t* __restrict__ A, const ushort_t* __restrict__ Bm,
                        int M, int N, int Kd, int ldk,
                        ushort_t* __restrict__ outB, float* __restrict__ outF,
                        const float* __restrict__ bias) {
  __shared__ alignas(16) ushort_t As[4][256 * 32];
  __shared__ alignas(16) ushort_t Bs[4][192 * 32];
  const int tid = threadIdx.x;
  const int lane = tid & 63;
  const int wave = tid >> 6;
  const int wm = wave >> 2, wn = wave & 3;

  const int gy = gridDim.y;
  int f = blockIdx.x + gridDim.x * blockIdx.y;
  {
    const int nwg = gridDim.x * gy;
    const int q = nwg >> 3, rr = nwg & 7;
    const int xcd = f & 7, ix = f >> 3;
    f = (xcd < rr ? xcd * (q + 1) : rr * (q + 1) + (xcd - rr) * q) + ix;
  }
  const int bx = f / gy, by = f - gy * bx;
  const int m0 = by * 256, n0 = bx * 192;

  floatx4 acc[8][3];
#pragma unroll
  for (int i = 0; i < 8; i++)
#pragma unroll
    for (int j = 0; j < 3; j++) acc[i][j] = (floatx4){0.f, 0.f, 0.f, 0.f};

  const int rloc = tid >> 2, cch = tid & 3;
  const int gcol = ((cch ^ ((rloc >> 1) & 3)) * 8);
  const ushort_t* gA = A + (size_t)(m0 + rloc) * ldk + gcol;
  const ushort_t* gB = Bm + (size_t)(n0 + rloc) * ldk + gcol;
  const int lofs = rloc * 32 + cch * 8;

#define STGA32(bufi, kofs)                                              \
  {                                                                     \
    async16(gA + (kofs), &As[bufi][lofs]);                              \
    async16(gA + (size_t)128 * ldk + (kofs), &As[bufi][4096 + lofs]);   \
  }
// rows 0..127 then rows 64..191 (64..127 double-written, same bytes)
#define STGB32(bufi, kofs)                                              \
  {                                                                     \
    async16(gB + (kofs), &Bs[bufi][lofs]);                              \
    async16(gB + (size_t)64 * ldk + (kofs), &Bs[bufi][2048 + lofs]);    \
  }

  const int NT = Kd >> 5;  // K-tiles of 32
  STGA32(0, 0) STGB32(0, 0)
  if (NT > 1) { STGA32(1, 32) STGB32(1, 32) }
  if (NT > 2) { STGA32(2, 64) STGB32(2, 64) }
  if (NT > 2) asm volatile("s_waitcnt vmcnt(8)" ::: "memory");
  else if (NT > 1) asm volatile("s_waitcnt vmcnt(4)" ::: "memory");
  else asm volatile("s_waitcnt vmcnt(0)" ::: "memory");
  __builtin_amdgcn_s_barrier();

  const int fr = lane & 15, fq = lane >> 4;
  const int co = ((fq ^ ((fr >> 1) & 3)) * 8);
  const int aoff = (wm * 128 + fr) * 32 + co;
  const int boff = (wn * 48 + fr) * 32 + co;

  for (int kt = 0; kt < NT; ++kt) {
    const int cb = kt & 3;
    const int pb = (kt + 3) & 3;
    const int kof = (kt + 3) * 32;
    const bool sp = (kt + 3) < NT;
    const ushort_t* Ab = As[cb];
    const ushort_t* Bb = Bs[cb];
    short8 av[4], bv[3];

    // ---- phase 0 ----
#pragma unroll
    for (int i = 0; i < 4; i++) av[i] = *(const short8*)(Ab + aoff + i * 512);
#pragma unroll
    for (int j = 0; j < 3; j++) bv[j] = *(const short8*)(Bb + boff + j * 512);
    if (sp) STGA32(pb, kof)
    __builtin_amdgcn_s_barrier();
    asm volatile("s_waitcnt lgkmcnt(0)" ::: "memory");
    __builtin_amdgcn_s_setprio(1);
#pragma unroll
    for (int i = 0; i < 4; i++)
#pragma unroll
      for (int j = 0; j < 3; j++)
        acc[i][j] = __builtin_amdgcn_mfma_f32_16x16x32_bf16(av[i], bv[j], acc[i][j], 0, 0, 0);
    __builtin_amdgcn_s_setprio(0);
    __builtin_amdgcn_s_barrier();

    // ---- phase 1 ----
#pragma unroll
    for (int i = 0; i < 4; i++) av[i] = *(const short8*)(Ab + aoff + 2048 + i * 512);
    if (sp) STGB32(pb, kof)
    __builtin_amdgcn_s_barrier();
    asm volatile("s_waitcnt lgkmcnt(0)" ::: "memory");
    __builtin_amdgcn_s_setprio(1);
#pragma unroll
    for (int i = 0; i < 4; i++)
#pragma unroll
      for (int j = 0; j < 3; j++)
        acc[4 + i][j] = __builtin_amdgcn_mfma_f32_16x16x32_bf16(av[i], bv[j], acc[4 + i][j], 0, 0, 0);
    __builtin_amdgcn_s_setprio(0);
    if (kt + 3 < NT) asm volatile("s_waitcnt vmcnt(8)" ::: "memory");
    else if (kt + 2 < NT) asm volatile("s_waitcnt vmcnt(4)" ::: "memory");
    else asm volatile("s_waitcnt vmcnt(0)" ::: "memory");
    __builtin_amdgcn_s_barrier();
  }
#undef STGA32
#undef STGB32

  const int crow = m0 + wm * 128 + (lane >> 4) * 4;
  const int ccol = n0 + wn * 48 + (lane & 15);
#pragma unroll
  for (int mt = 0; mt < 8; mt++)
#pragma unroll
    for (int nt = 0; nt < 3; nt++) {
      floatx4 a = acc[mt][nt];
#pragma unroll
      for (int r = 0; r < 4; r++) {
        const int gm = crow + mt * 16 + r;
        const int gn = ccol + nt * 16;
        outB[(size_t)gm * N + gn] = f2b(a[r]);
      }
    }
}

// ---------------- split-K=2 reduction: out += P0 + P1 -----------------------
__launch_bounds__(256)
__global__ void reduce2(const float4* __restrict__ P, float4* __restrict__ out, int n4) {
  int i = blockIdx.x * blockDim.x + threadIdx.x;
  int st = gridDim.x * blockDim.x;
  for (; i < n4; i += st) {
    float4 a = out[i];
    float4 p0 = P[i], p1 = P[i + 1048576];
    a.x += p0.x + p1.x;
    a.y += p0.y + p1.y;
    a.z += p0.z + p1.z;
    a.w += p0.w + p1.w;
    out[i] = a;
  }
}

// ---------------- attention (degenerate mask -> diag + suffix sum) ----------
// z[q] = (e_q*v[q] + sum_{p>q} v[p]) / (e_q + (S-1-q)), e_q = exp(q.k/8)
__launch_bounds__(256)
__global__ void attn1(const ushort_t* __restrict__ qkv,
                      float* __restrict__ eG, float* __restrict__ psumG) {
  const int c = blockIdx.x & 63;
  const int i = (blockIdx.x >> 6) & 15;
  const int b = blockIdx.x >> 10;
  const int t = threadIdx.x;
  const int sg = t >> 3, h8 = (t & 7) * 8;
  const int s = c * 32 + sg;
  const size_t rb = (size_t)b * 2048 * 3072 + (size_t)s * 3072 + i * 64 + h8;
  short8 q8 = *(const short8*)(qkv + rb);
  short8 k8 = *(const short8*)(qkv + rb + 1024);
  short8 v8 = *(const short8*)(qkv + rb + 2048);
  float d = 0.f;
  float vf[8];
#pragma unroll
  for (int j = 0; j < 8; j++) {
    float qf = b2f((ushort_t)q8[j]);
    float kf = b2f((ushort_t)k8[j]);
    vf[j] = b2f((ushort_t)v8[j]);
    d += qf * kf;
  }
  d += __shfl_xor(d, 1, 64);
  d += __shfl_xor(d, 2, 64);
  d += __shfl_xor(d, 4, 64);
  if ((t & 7) == 0) eG[((size_t)(b * 16 + i)) * 2048 + s] = __expf(d * 0.125f);
  __shared__ float vs[32][68];  // +4 pad: b128 writes hit all 8 bank slots
#pragma unroll
  for (int j = 0; j < 8; j += 4)
    *(float4*)&vs[sg][h8 + j] = make_float4(vf[j], vf[j + 1], vf[j + 2], vf[j + 3]);
  __syncthreads();
  if (t < 64) {
    float acc = 0.f;
#pragma unroll 8
    for (int sgi = 0; sgi < 32; sgi++) acc += vs[sgi][t];
    psumG[(((size_t)(b * 16 + i)) * 64 + c) * 64 + t] = acc;
  }
}

// Pass 2 (R16): rcp hoisted off the serial chain; 4-acc suffix sum.
__launch_bounds__(256)
__global__ void attn2(const ushort_t* __restrict__ qkv,
                      const float* __restrict__ eG, const float* __restrict__ psumG,
                      ushort_t* __restrict__ Z) {
  const int wave = threadIdx.x >> 6, h = threadIdx.x & 63;
  const int c = (blockIdx.x & 15) * 4 + wave;
  const int i = (blockIdx.x >> 4) & 15;
  const int b = blockIdx.x >> 8;
  const size_t rowbase = (size_t)b * 2048 * 3072;
  const size_t pbase = ((size_t)(b * 16 + i)) * 64;
  float r0 = 0.f, r1 = 0.f, r2 = 0.f, r3 = 0.f;
  {
    int cc = c + 1;
    for (; cc + 3 < 64; cc += 4) {
      r0 += psumG[(pbase + cc) * 64 + h];
      r1 += psumG[(pbase + cc + 1) * 64 + h];
      r2 += psumG[(pbase + cc + 2) * 64 + h];
      r3 += psumG[(pbase + cc + 3) * 64 + h];
    }
    for (; cc < 64; cc++) r0 += psumG[(pbase + cc) * 64 + h];
  }
  float run = (r0 + r1) + (r2 + r3);
  const size_t ebase = ((size_t)(b * 16 + i)) * 2048;
  for (int t4 = 1; t4 >= 0; t4--) {
    float vv[16], num[16], rcp[16];
#pragma unroll
    for (int j = 0; j < 16; j++) {
      const int s = c * 32 + t4 * 16 + j;
      vv[j] = b2f(qkv[rowbase + (size_t)s * 3072 + 2048 + i * 64 + h]);
      float e = eG[ebase + s];
      num[j] = e * vv[j];
      float d = e + (float)(2047 - s);
      float r = __builtin_amdgcn_rcpf(d);
      rcp[j] = r * (2.f - d * r);  // one Newton step
    }
#pragma unroll
    for (int j = 15; j >= 0; j--) {
      const int s = c * 32 + t4 * 16 + j;
      float z = (num[j] + run) * rcp[j];
      Z[((size_t)b * 2048 + s) * 1024 + i * 64 + h] = f2b(z);
      run += vv[j];
    }
  }
}

// ---------------- launch ----------------------------------------------------
extern "C" void kernel_launch(void* const* d_in, const int* in_sizes, int n_in,
                              void* d_out, int out_size, void* d_ws, size_t ws_size,
                              hipStream_t stream) {
  const float* x     = (const float*)d_in[0];
  const float* W_Q   = (const float*)d_in[1];
  const float* W_K   = (const float*)d_in[2];
  const float* W_V   = (const float*)d_in[3];
  const float* W_O   = (const float*)d_in[4];
  const float* W_in  = (const float*)d_in[5];
  const float* b_in  = (const float*)d_in[6];
  const float* W_out = (const float*)d_in[7];
  const float* b_out = (const float*)d_in[8];
  float* out = (float*)d_out;

  // ws layout (max 104 MB).
  // P (32 MB) aliases [0,32): Xb/Wqkv/WOb/Z/QKV[0,8MB) all dead by MODE3
  // (stream-ordered). eG/psumG live inside Hb's region [72,104): consumed by
  // attn2 BEFORE MLP-in writes Hb, so no conflict.
  char* base = (char*)d_ws;
  const size_t MB = 1048576;
  ushort_t* Xb    = (ushort_t*)(base + 0 * MB);    // 8 MB
  ushort_t* Wqkv  = (ushort_t*)(base + 8 * MB);    // 6 MB
  ushort_t* WOb   = (ushort_t*)(base + 14 * MB);   // 2 MB
  ushort_t* Z     = (ushort_t*)(base + 16 * MB);   // 8 MB
  ushort_t* QKV   = (ushort_t*)(base + 24 * MB);   // 24 MB
  ushort_t* midb  = (ushort_t*)(base + 48 * MB);   // 8 MB
  ushort_t* Winb  = (ushort_t*)(base + 56 * MB);   // 8 MB
  ushort_t* Woutb = (ushort_t*)(base + 64 * MB);   // 8 MB
  ushort_t* Hb    = (ushort_t*)(base + 72 * MB);   // 32 MB
  float*    P     = (float*)(base + 0 * MB);       // 32 MB [0,32) alias
  float*    psumG = (float*)(base + 72 * MB);            // 512 KB (pre-MLP-in)
  float*    eG    = (float*)(base + 72 * MB + 524288);   // 256 KB (pre-MLP-in)

  Cvt7 ca;
  ca.src[0] = x;     ca.dst[0] = Xb;               ca.scale[0] = 1.f;
  ca.src[1] = W_Q;   ca.dst[1] = Wqkv;             ca.scale[1] = 1.f;
  ca.src[2] = W_K;   ca.dst[2] = Wqkv + 1048576;   ca.scale[2] = 1.f;
  ca.src[3] = W_V;   ca.dst[3] = Wqkv + 2097152;   ca.scale[3] = 1.f;
  ca.src[4] = W_O;   ca.dst[4] = WOb;              ca.scale[4] = 2.f;  // fold mid=2*attn_out
  ca.src[5] = W_in;  ca.dst[5] = Winb;             ca.scale[5] = 1.f;
  ca.src[6] = W_out; ca.dst[6] = Woutb;            ca.scale[6] = 1.f;
  unsigned n4s[7] = {1048576, 262144, 262144, 262144, 262144, 1048576, 1048576};
  unsigned acc4 = 0;
  for (int j = 0; j < 7; j++) { ca.start[j] = acc4; acc4 += n4s[j]; }
  ca.start[7] = acc4;
  cvt_all<<<dim3((acc4 + 255) / 256), dim3(256), 0, stream>>>(ca);

  // QKV = X * Wqkv^T [4096,3072]: 256x192 tile, grid 16x16 = 256 blocks.
  gemm192<0><<<dim3(16, 16), 512, 0, stream>>>(Xb, Wqkv, 4096, 3072, 1024, 1024,
                                               QKV, nullptr, nullptr);
  // attention -> Z [4096, 1024] bf16
  attn1<<<dim3(2048), 256, 0, stream>>>(QKV, eG, psumG);
  attn2<<<dim3(512), 256, 0, stream>>>(QKV, eG, psumG, Z);
  // mid = Z*(2*W_O)^T: legacy path, y-coloc (full B = 2 MB fits L2).
  gemm_bt<1, 2, 1><<<dim3(8, 64), 256, 0, stream>>>(Z, WOb, 4096, 1024, 1024, 1024,
                                                    midb, out, b_out);
  // H = relu(mid*W_in^T + b_in) [4096,4096]: gemm256 R11 (best measured).
  gemm256<2><<<dim3(16, 16), 512, 0, stream>>>(midb, Winb, 4096, 4096, 1024, 1024,
                                               Hb, nullptr, b_in);
  // P[z] = H slice * W_out^T: split-K=2, SWZ=3 (R25): 4bx x 16by cluster/XCD
  // -> per-XCD A footprint 4 MB (L2-sized) vs cluster2's 8 MB.
  gemm_bt<3, 2, 3><<<dim3(8, 64, 2), 256, 0, stream>>>(Hb, Woutb, 4096, 1024, 2048, 4096,
                                                       nullptr, P, nullptr);
  // out += P0 + P1
  reduce2<<<dim3(1024), 256, 0, stream>>>((const float4*)P, (float4*)out, 1048576);
}